// Round 6
// baseline (279.566 us; speedup 1.0000x reference)
//
#include <hip/hip_runtime.h>

#define Nn     20000
#define IN_CH  512
#define C1     512      // H1*HID
#define H1n    8
#define HIDn   64
#define OUT_CH 16
#define En     320000
#define EPn    340000   // E + N self-loops
#define NEG    0.2f

typedef __attribute__((ext_vector_type(8))) short bf16x8;
typedef __attribute__((ext_vector_type(4))) float f32x4;

// ---------------- fp32 -> bf16 helpers (RNE) --------------------------------
__device__ inline unsigned short bf16_rne(float f) {
  unsigned int u = __float_as_uint(f);
  return (unsigned short)((u + 0x7fffu + ((u >> 16) & 1u)) >> 16);
}
__device__ inline float bf16_f(unsigned short u) {
  return __uint_as_float(((unsigned int)u) << 16);
}

// x -> bf16 (hi only)
__global__ __launch_bounds__(256) void cvt_kernel(
    const float* __restrict__ in, unsigned short* __restrict__ outb, int n8)
{
  int i = blockIdx.x * 256 + threadIdx.x;
  if (i >= n8) return;
  float4 f0 = ((const float4*)in)[i * 2];
  float4 f1 = ((const float4*)in)[i * 2 + 1];
  float f[8] = {f0.x, f0.y, f0.z, f0.w, f1.x, f1.y, f1.z, f1.w};
  unsigned short h[8];
#pragma unroll
  for (int j = 0; j < 8; j++) h[j] = bf16_rne(f[j]);
  ushort4 hv0 = {h[0], h[1], h[2], h[3]}, hv1 = {h[4], h[5], h[6], h[7]};
  ((ushort4*)outb)[i * 2] = hv0; ((ushort4*)outb)[i * 2 + 1] = hv1;
}

// W -> (hi, lo) bf16 split
__global__ __launch_bounds__(256) void split_kernel(
    const float* __restrict__ in, unsigned short* __restrict__ hi,
    unsigned short* __restrict__ lo, int n8)
{
  int i = blockIdx.x * 256 + threadIdx.x;
  if (i >= n8) return;
  float4 f0 = ((const float4*)in)[i * 2];
  float4 f1 = ((const float4*)in)[i * 2 + 1];
  float f[8] = {f0.x, f0.y, f0.z, f0.w, f1.x, f1.y, f1.z, f1.w};
  unsigned short h[8], l[8];
#pragma unroll
  for (int j = 0; j < 8; j++) {
    unsigned short hb = bf16_rne(f[j]);
    h[j] = hb;
    l[j] = bf16_rne(f[j] - bf16_f(hb));
  }
  ushort4 hv0 = {h[0], h[1], h[2], h[3]}, hv1 = {h[4], h[5], h[6], h[7]};
  ushort4 lv0 = {l[0], l[1], l[2], l[3]}, lv1 = {l[4], l[5], l[6], l[7]};
  ((ushort4*)hi)[i * 2] = hv0; ((ushort4*)hi)[i * 2 + 1] = hv1;
  ((ushort4*)lo)[i * 2] = lv0; ((ushort4*)lo)[i * 2 + 1] = lv1;
}

// ------ GEMM1 (2-term split MFMA): h1b[N,512](bf16) = x @ W1^T --------------
#define GLL(gp, lp) __builtin_amdgcn_global_load_lds( \
    (const __attribute__((address_space(1))) void*)(gp), \
    (__attribute__((address_space(3))) void*)(lp), 16, 0, 0)

// involutive chunk swizzle: spreads 64B-stride rows across all 8 bank groups
#define SWZ(c) ((c) ^ (((c) >> 3) & 3))

__global__ __launch_bounds__(256, 2) void gemm1_mfma(
    const unsigned short* __restrict__ Ab,
    const unsigned short* __restrict__ Bhi, const unsigned short* __restrict__ Blo,
    unsigned short* __restrict__ Cb)
{
  __shared__ unsigned short sA[128 * 32];
  __shared__ unsigned short sBhi[128 * 32], sBlo[128 * 32];
  int t = threadIdx.x;
  int bm = blockIdx.x, bn = blockIdx.y;
  int lane = t & 63, w = t >> 6;

  // staging: 512 16B-chunks per tile; LDS slot q holds tile-chunk SWZ(q)
  int slot0 = w * 128 + lane;
  int slot1 = slot0 + 64;
  int cb0 = w * 128, cb1 = w * 128 + 64;     // wave-uniform LDS base chunks
  int cs0 = SWZ(slot0), cs1 = SWZ(slot1);    // tile-chunk fetched by this lane
  int ar0 = bm * 128 + (cs0 >> 2); if (ar0 > Nn - 1) ar0 = Nn - 1;
  int ar1 = bm * 128 + (cs1 >> 2); if (ar1 > Nn - 1) ar1 = Nn - 1;
  int br0 = bn * 128 + (cs0 >> 2);
  int br1 = bn * 128 + (cs1 >> 2);
  size_t offA0 = (size_t)ar0 * IN_CH + (cs0 & 3) * 8;
  size_t offA1 = (size_t)ar1 * IN_CH + (cs1 & 3) * 8;
  size_t offB0 = (size_t)br0 * IN_CH + (cs0 & 3) * 8;
  size_t offB1 = (size_t)br1 * IN_CH + (cs1 & 3) * 8;

  int wm = (w >> 1) * 64, wn = (w & 1) * 64;
  int lr = lane & 15, kb = lane >> 4;

  f32x4 acc[4][4] = {};

  for (int k0 = 0; k0 < IN_CH; k0 += 32) {
    __syncthreads();                      // prev iter's LDS reads done
    GLL(Ab  + offA0 + k0, sA   + cb0 * 8);
    GLL(Ab  + offA1 + k0, sA   + cb1 * 8);
    GLL(Bhi + offB0 + k0, sBhi + cb0 * 8);
    GLL(Bhi + offB1 + k0, sBhi + cb1 * 8);
    GLL(Blo + offB0 + k0, sBlo + cb0 * 8);
    GLL(Blo + offB1 + k0, sBlo + cb1 * 8);
    __syncthreads();                      // loads landed

    bf16x8 ah[4], bh[4], bl[4];
#pragma unroll
    for (int i = 0; i < 4; i++) {
      int rca = (wm + i * 16 + lr) * 4 + kb;
      int sca = SWZ(rca);
      ah[i] = *(const bf16x8*)&sA[sca * 8];
      int rcb = (wn + i * 16 + lr) * 4 + kb;
      int scb = SWZ(rcb);
      bh[i] = *(const bf16x8*)&sBhi[scb * 8];
      bl[i] = *(const bf16x8*)&sBlo[scb * 8];
    }
#pragma unroll
    for (int i = 0; i < 4; i++)
#pragma unroll
      for (int j = 0; j < 4; j++) {
        acc[i][j] = __builtin_amdgcn_mfma_f32_16x16x32_bf16(ah[i], bh[j], acc[i][j], 0, 0, 0);
        acc[i][j] = __builtin_amdgcn_mfma_f32_16x16x32_bf16(ah[i], bl[j], acc[i][j], 0, 0, 0);
      }
  }

  int lq = lane >> 4;
#pragma unroll
  for (int i = 0; i < 4; i++) {
    int r0 = bm * 128 + wm + i * 16 + lq * 4;
#pragma unroll
    for (int j = 0; j < 4; j++) {
      int cc = bn * 128 + wn + j * 16 + lr;
#pragma unroll
      for (int q = 0; q < 4; q++) {
        int r = r0 + q;
        if (r < Nn) Cb[(size_t)r * C1 + cc] = bf16_rne(acc[i][j][q]);
      }
    }
  }
}

// ------------- per-(node,head) attention logits from bf16 h1 ----------------
__global__ __launch_bounds__(256) void logits1_kernel(
    const unsigned short* __restrict__ h1b, const float* __restrict__ att_s,
    const float* __restrict__ att_d, float* __restrict__ as1, float* __restrict__ ad1)
{
  int wave = threadIdx.x >> 6, lane = threadIdx.x & 63;
  int p = blockIdx.x * 4 + wave;            // pair index n*8+h
  if (p >= Nn * H1n) return;
  int n = p >> 3, h = p & 7;
  float v = bf16_f(h1b[(size_t)n * C1 + h * HIDn + lane]);
  float s = v * att_s[h * HIDn + lane];
  float d = v * att_d[h * HIDn + lane];
#pragma unroll
  for (int off = 32; off; off >>= 1) {
    s += __shfl_xor(s, off);
    d += __shfl_xor(d, off);
  }
  if (lane == 0) { as1[p] = s; ad1[p] = d; }
}

// --------------------------- CSR build by dst -------------------------------
__global__ void hist_kernel(const int* __restrict__ ei, int* __restrict__ cnt)
{
  int e = blockIdx.x * 256 + threadIdx.x;
  if (e >= EPn) return;
  int d = (e < En) ? ei[En + e] : (e - En);
  atomicAdd(&cnt[d], 1);
}

__global__ __launch_bounds__(1024) void scan_kernel(
    const int* __restrict__ cnt, int* __restrict__ row)
{
  __shared__ int wsum[16];
  int t = threadIdx.x;
  int base = t * 20;
  int v[20];
  int s = 0;
#pragma unroll
  for (int j = 0; j < 20; j++) {
    int i = base + j;
    int c = (i < Nn) ? cnt[i] : 0;
    v[j] = s;
    s += c;
  }
  int lane = t & 63, w = t >> 6;
  int incl = s;
#pragma unroll
  for (int off = 1; off < 64; off <<= 1) {
    int o = __shfl_up(incl, off);
    if (lane >= off) incl += o;
  }
  if (lane == 63) wsum[w] = incl;
  __syncthreads();
  if (w == 0) {
    int ws = (lane < 16) ? wsum[lane] : 0;
#pragma unroll
    for (int off = 1; off < 16; off <<= 1) {
      int o = __shfl_up(ws, off);
      if (lane >= off) ws += o;
    }
    if (lane < 16) wsum[lane] = ws;
  }
  __syncthreads();
  int excl = ((w > 0) ? wsum[w - 1] : 0) + incl - s;
#pragma unroll
  for (int j = 0; j < 20; j++) {
    int i = base + j;
    if (i < Nn) row[i] = excl + v[j];
  }
  if (t == 0) row[Nn] = EPn;
}

__global__ void scatter_kernel(const int* __restrict__ ei, const int* __restrict__ row,
                               int* __restrict__ cur, int* __restrict__ csr)
{
  int e = blockIdx.x * 256 + threadIdx.x;
  if (e >= EPn) return;
  int s, d;
  if (e < En) { s = ei[e]; d = ei[En + e]; }
  else        { s = e - En; d = e - En; }
  int pos = row[d] + atomicAdd(&cur[d], 1);
  csr[pos] = s;
}

// ----- layer-1 softmax + aggregate (block per dst) --------------------------
// 4 waves; wave w takes edges e == w (mod 4) and gathers the FULL 512-ch row
// at 16B/lane (8 ch/lane, head hq = lane>>3).  Alpha for an 8-edge chunk is
// computed once per (edge,head) -- lane (li,hq) -- staged in the wave's
// PRIVATE LDS slice (within-wave ordering, no barrier).  Partials combined
// via write-once LDS slots + ONE barrier.
__global__ __launch_bounds__(256) void agg1_kernel(
    const int* __restrict__ row, const int* __restrict__ csr,
    const unsigned short* __restrict__ h1b, const float* __restrict__ as1,
    const float* __restrict__ adv, const float* __restrict__ b1,
    float* __restrict__ out)
{
  __shared__ float walpha[4][8][8];   // [wave][edge-in-chunk][head]
  __shared__ float part[3][64][8];    // partials from waves 1..3

  int d = blockIdx.x;
  int beg = row[d], end = row[d + 1];
  int deg = end - beg;
  int t = threadIdx.x, lane = t & 63, w = t >> 6;
  int hq = lane >> 3;                 // this lane's head (8 ch/lane)
  int li = lane & 7;                  // edge slot this lane stages

  float4 ad0 = *(const float4*)&adv[d * 8];
  float4 ad1v = *(const float4*)&adv[d * 8 + 4];

  // pass 1: per-head max over all edges (all 4 waves duplicate; cheap)
  float m[8], z[8];
#pragma unroll
  for (int h = 0; h < 8; h++) m[h] = -1e30f;
  for (int e = beg + lane; e < end; e += 64) {
    int s = csr[e];
    float4 a0 = *(const float4*)&as1[s * 8];
    float4 a1 = *(const float4*)&as1[s * 8 + 4];
    float av[8] = {a0.x, a0.y, a0.z, a0.w, a1.x, a1.y, a1.z, a1.w};
    float adv8[8] = {ad0.x, ad0.y, ad0.z, ad0.w, ad1v.x, ad1v.y, ad1v.z, ad1v.w};
#pragma unroll
    for (int h = 0; h < 8; h++) {
      float v = av[h] + adv8[h];
      v = v >= 0.f ? v : NEG * v;
      m[h] = fmaxf(m[h], v);
    }
  }
#pragma unroll
  for (int h = 0; h < 8; h++)
#pragma unroll
    for (int off = 32; off; off >>= 1) m[h] = fmaxf(m[h], __shfl_xor(m[h], off));

  // pass 2: per-head denominator
#pragma unroll
  for (int h = 0; h < 8; h++) z[h] = 0.f;
  for (int e = beg + lane; e < end; e += 64) {
    int s = csr[e];
    float4 a0 = *(const float4*)&as1[s * 8];
    float4 a1 = *(const float4*)&as1[s * 8 + 4];
    float av[8] = {a0.x, a0.y, a0.z, a0.w, a1.x, a1.y, a1.z, a1.w};
    float adv8[8] = {ad0.x, ad0.y, ad0.z, ad0.w, ad1v.x, ad1v.y, ad1v.z, ad1v.w};
#pragma unroll
    for (int h = 0; h < 8; h++) {
      float v = av[h] + adv8[h];
      v = v >= 0.f ? v : NEG * v;
      z[h] += __expf(v - m[h]);
    }
  }
#pragma unroll
  for (int h = 0; h < 8; h++)
#pragma unroll
    for (int off = 32; off; off >>= 1) z[h] += __shfl_xor(z[h], off);

  // one-time per-lane head constants (static 7-deep selects)
  float mH  = hq == 0 ? m[0] : hq == 1 ? m[1] : hq == 2 ? m[2] : hq == 3 ? m[3]
            : hq == 4 ? m[4] : hq == 5 ? m[5] : hq == 6 ? m[6] : m[7];
  float zH  = hq == 0 ? z[0] : hq == 1 ? z[1] : hq == 2 ? z[2] : hq == 3 ? z[3]
            : hq == 4 ? z[4] : hq == 5 ? z[5] : hq == 6 ? z[6] : z[7];
  float adH = hq == 0 ? ad0.x : hq == 1 ? ad0.y : hq == 2 ? ad0.z : hq == 3 ? ad0.w
            : hq == 4 ? ad1v.x : hq == 5 ? ad1v.y : hq == 6 ? ad1v.z : ad1v.w;
  float rzH = 1.f / zH;

  // this wave's edge class: e = beg + w + 4*j, j in [0, nj)
  int nj = (deg > w) ? ((deg - w + 3) >> 2) : 0;
  size_t chb = (size_t)8 * lane;       // 8 channels per lane

  float a0 = 0.f, a1 = 0.f, a2 = 0.f, a3 = 0.f;
  float a4 = 0.f, a5 = 0.f, a6 = 0.f, a7 = 0.f;
  for (int jb = 0; jb < nj; jb += 8) {
    int cnt = min(8, nj - jb);
    int jj = jb + li;
    if (jj < nj) {
      int s = csr[beg + w + 4 * jj];
      float v = as1[s * 8 + hq] + adH;
      v = v >= 0.f ? v : NEG * v;
      walpha[w][li][hq] = __expf(v - mH) * rzH;   // single writer per slot
    }
    // within-wave ds_write -> ds_read: ordered by lgkmcnt, no barrier
    for (int i = 0; i < cnt; i++) {
      int s = csr[beg + w + 4 * (jb + i)];        // wave-uniform broadcast
      float al = walpha[w][i][hq];
      bf16x8 hv = *(const bf16x8*)&h1b[(size_t)s * C1 + chb];
      a0 = fmaf(al, bf16_f((unsigned short)hv[0]), a0);
      a1 = fmaf(al, bf16_f((unsigned short)hv[1]), a1);
      a2 = fmaf(al, bf16_f((unsigned short)hv[2]), a2);
      a3 = fmaf(al, bf16_f((unsigned short)hv[3]), a3);
      a4 = fmaf(al, bf16_f((unsigned short)hv[4]), a4);
      a5 = fmaf(al, bf16_f((unsigned short)hv[5]), a5);
      a6 = fmaf(al, bf16_f((unsigned short)hv[6]), a6);
      a7 = fmaf(al, bf16_f((unsigned short)hv[7]), a7);
    }
  }

  // combine partials (write-once slots, one barrier)
  if (w) {
    float* ps = part[w - 1][lane];
    ps[0] = a0; ps[1] = a1; ps[2] = a2; ps[3] = a3;
    ps[4] = a4; ps[5] = a5; ps[6] = a6; ps[7] = a7;
  }
  __syncthreads();
  if (w == 0) {
#pragma unroll
    for (int q = 0; q < 3; q++) {
      const float* ps = part[q][lane];
      a0 += ps[0]; a1 += ps[1]; a2 += ps[2]; a3 += ps[3];
      a4 += ps[4]; a5 += ps[5]; a6 += ps[6]; a7 += ps[7];
    }
    float4 b0 = *(const float4*)&b1[chb];
    float4 b4 = *(const float4*)&b1[chb + 4];
    float o0 = a0 + b0.x, o1 = a1 + b0.y, o2 = a2 + b0.z, o3 = a3 + b0.w;
    float o4 = a4 + b4.x, o5 = a5 + b4.y, o6 = a6 + b4.z, o7 = a7 + b4.w;
    float4 r0 = {o0 > 0.f ? o0 : 0.f, o1 > 0.f ? o1 : 0.f,
                 o2 > 0.f ? o2 : 0.f, o3 > 0.f ? o3 : 0.f};
    float4 r4 = {o4 > 0.f ? o4 : 0.f, o5 > 0.f ? o5 : 0.f,
                 o6 > 0.f ? o6 : 0.f, o7 > 0.f ? o7 : 0.f};
    *(float4*)&out[(size_t)d * C1 + chb] = r0;
    *(float4*)&out[(size_t)d * C1 + chb + 4] = r4;
  }
}

// --------- layer-2 transform: h2[N,16] = relu1 @ W2^T; a_s2, a_d2 -----------
__global__ __launch_bounds__(256) void l2_kernel(
    const float* __restrict__ in, const float* __restrict__ W2,
    const float* __restrict__ att_s, const float* __restrict__ att_d,
    float* __restrict__ h2, float* __restrict__ as2, float* __restrict__ ad2)
{
  __shared__ float W2s[OUT_CH * 512];
  int t = threadIdx.x;
  for (int i = t * 4; i < OUT_CH * 512; i += 1024)
    *(float4*)&W2s[i] = *(const float4*)&W2[i];
  __syncthreads();
  int wave = t >> 6, lane = t & 63;
  int n = blockIdx.x * 4 + wave;   // grid = N/4 exactly
  const float* xr = in + (size_t)n * 512;
  float acc[16] = {};
  for (int k = lane; k < 512; k += 64) {
    float xv = xr[k];
#pragma unroll
    for (int j = 0; j < 16; j++) acc[j] = fmaf(xv, W2s[j * 512 + k], acc[j]);
  }
#pragma unroll
  for (int j = 0; j < 16; j++)
#pragma unroll
    for (int off = 32; off; off >>= 1) acc[j] += __shfl_xor(acc[j], off);
  if (lane == 0) {
    float s = 0.f, dd = 0.f;
#pragma unroll
    for (int j = 0; j < 16; j++) {
      h2[(size_t)n * 16 + j] = acc[j];
      s  = fmaf(acc[j], att_s[j], s);
      dd = fmaf(acc[j], att_d[j], dd);
    }
    as2[n] = s; ad2[n] = dd;
  }
}

// ------- layer-2 softmax + aggregate (one wave per dst), fused +b2 ----------
__global__ __launch_bounds__(256) void agg2_kernel(
    const int* __restrict__ row, const int* __restrict__ csr,
    const float* __restrict__ h2, const float* __restrict__ as2,
    const float* __restrict__ ad2, const float* __restrict__ b2,
    float* __restrict__ out)
{
  int wave = threadIdx.x >> 6, lane = threadIdx.x & 63;
  int d = blockIdx.x * 4 + wave;   // grid = N/4 exactly
  int beg = row[d], end = row[d + 1];
  float add = ad2[d];

  float m = -1e30f;
  for (int e = beg + lane; e < end; e += 64) {
    float v = as2[csr[e]] + add;
    v = (v >= 0.f) ? v : NEG * v;
    m = fmaxf(m, v);
  }
#pragma unroll
  for (int off = 32; off; off >>= 1) m = fmaxf(m, __shfl_xor(m, off));
  float z = 0.f;
  for (int e = beg + lane; e < end; e += 64) {
    float v = as2[csr[e]] + add;
    v = (v >= 0.f) ? v : NEG * v;
    z += __expf(v - m);
  }
#pragma unroll
  for (int off = 32; off; off >>= 1) z += __shfl_xor(z, off);

  int c = lane & 15;
  float acc = 0.f;
  for (int e = beg + (lane >> 4); e < end; e += 4) {
    int s = csr[e];
    float v = as2[s] + add;
    v = (v >= 0.f) ? v : NEG * v;
    float al = __expf(v - m) / z;
    acc = fmaf(al, h2[(size_t)s * 16 + c], acc);
  }
  acc += __shfl_xor(acc, 16);
  acc += __shfl_xor(acc, 32);
  if (lane < 16) out[(size_t)d * 16 + lane] = acc + b2[lane];
}

extern "C" void kernel_launch(void* const* d_in, const int* in_sizes, int n_in,
                              void* d_out, int out_size, void* d_ws, size_t ws_size,
                              hipStream_t stream)
{
  const float* x    = (const float*)d_in[0];
  const int*   ei   = (const int*)d_in[1];
  const float* W1   = (const float*)d_in[2];
  const float* asv1 = (const float*)d_in[3];
  const float* adv1 = (const float*)d_in[4];
  const float* b1   = (const float*)d_in[5];
  const float* W2   = (const float*)d_in[6];
  const float* asv2 = (const float*)d_in[7];
  const float* adv2 = (const float*)d_in[8];
  const float* b2   = (const float*)d_in[9];
  float* out = (float*)d_out;

  // workspace layout (16B-aligned regions)
  unsigned short* h1b = (unsigned short*)d_ws;               // N*512 bf16
  float* relu1 = (float*)(h1b + (size_t)Nn * C1);            // N*512 f32 (aliased x_b pre-agg1)
  float* as1   = relu1 + (size_t)Nn * C1;                    // N*8
  float* ad1   = as1 + (size_t)Nn * H1n;                     // N*8
  float* h2    = ad1 + (size_t)Nn * H1n;                     // N*16
  float* as2   = h2 + (size_t)Nn * OUT_CH;                   // N
  float* ad2   = as2 + Nn;                                   // N
  int* csr  = (int*)(ad2 + Nn);                              // E+N (aliased W_hi/W_lo pre-scatter)
  int* cnt  = csr + EPn;                                     // N
  int* rowp = cnt + Nn;                                      // N+1
  int* cur  = rowp + Nn + 1;                                 // N

  unsigned short* x_b  = (unsigned short*)relu1;             // N*512 bf16
  unsigned short* w_hi = (unsigned short*)csr;               // 512*512 bf16
  unsigned short* w_lo = w_hi + (size_t)C1 * IN_CH;          // 512*512 bf16

  hipMemsetAsync(cnt, 0, Nn * sizeof(int), stream);
  hipMemsetAsync(cur, 0, Nn * sizeof(int), stream);

  cvt_kernel<<<(Nn * IN_CH / 8 + 255) / 256, 256, 0, stream>>>(x, x_b, Nn * IN_CH / 8);
  split_kernel<<<(C1 * IN_CH / 8 + 255) / 256, 256, 0, stream>>>(W1, w_hi, w_lo, C1 * IN_CH / 8);

  dim3 g1(157, 4);
  gemm1_mfma<<<g1, 256, 0, stream>>>(x_b, w_hi, w_lo, h1b);

  logits1_kernel<<<(Nn * H1n) / 4, 256, 0, stream>>>(h1b, asv1, adv1, as1, ad1);
  hist_kernel<<<(EPn + 255) / 256, 256, 0, stream>>>(ei, cnt);
  scan_kernel<<<1, 1024, 0, stream>>>(cnt, rowp);
  scatter_kernel<<<(EPn + 255) / 256, 256, 0, stream>>>(ei, rowp, cur, csr);  // overwrites w_hi/w_lo (gemm done)
  agg1_kernel<<<Nn, 256, 0, stream>>>(rowp, csr, h1b, as1, ad1, b1, relu1);   // overwrites x_b (gemm done)
  l2_kernel<<<Nn / 4, 256, 0, stream>>>(relu1, W2, asv2, adv2, h2, as2, ad2);
  agg2_kernel<<<Nn / 4, 256, 0, stream>>>(rowp, csr, h2, as2, ad2, b2, out);
}

// Round 7
// 254.209 us; speedup vs baseline: 1.0998x; 1.0998x over previous
//
#include <hip/hip_runtime.h>

#define Nn     20000
#define IN_CH  512
#define C1     512      // H1*HID
#define H1n    8
#define HIDn   64
#define OUT_CH 16
#define En     320000
#define EPn    340000   // E + N self-loops
#define NEG    0.2f

typedef __attribute__((ext_vector_type(8))) short bf16x8;
typedef __attribute__((ext_vector_type(4))) float f32x4;

// ---------------- fp32 -> bf16 helpers (RNE) --------------------------------
__device__ inline unsigned short bf16_rne(float f) {
  unsigned int u = __float_as_uint(f);
  return (unsigned short)((u + 0x7fffu + ((u >> 16) & 1u)) >> 16);
}
__device__ inline float bf16_f(unsigned short u) {
  return __uint_as_float(((unsigned int)u) << 16);
}

// x -> bf16 (hi only)
__global__ __launch_bounds__(256) void cvt_kernel(
    const float* __restrict__ in, unsigned short* __restrict__ outb, int n8)
{
  int i = blockIdx.x * 256 + threadIdx.x;
  if (i >= n8) return;
  float4 f0 = ((const float4*)in)[i * 2];
  float4 f1 = ((const float4*)in)[i * 2 + 1];
  float f[8] = {f0.x, f0.y, f0.z, f0.w, f1.x, f1.y, f1.z, f1.w};
  unsigned short h[8];
#pragma unroll
  for (int j = 0; j < 8; j++) h[j] = bf16_rne(f[j]);
  ushort4 hv0 = {h[0], h[1], h[2], h[3]}, hv1 = {h[4], h[5], h[6], h[7]};
  ((ushort4*)outb)[i * 2] = hv0; ((ushort4*)outb)[i * 2 + 1] = hv1;
}

// W -> (hi, lo) bf16 split
__global__ __launch_bounds__(256) void split_kernel(
    const float* __restrict__ in, unsigned short* __restrict__ hi,
    unsigned short* __restrict__ lo, int n8)
{
  int i = blockIdx.x * 256 + threadIdx.x;
  if (i >= n8) return;
  float4 f0 = ((const float4*)in)[i * 2];
  float4 f1 = ((const float4*)in)[i * 2 + 1];
  float f[8] = {f0.x, f0.y, f0.z, f0.w, f1.x, f1.y, f1.z, f1.w};
  unsigned short h[8], l[8];
#pragma unroll
  for (int j = 0; j < 8; j++) {
    unsigned short hb = bf16_rne(f[j]);
    h[j] = hb;
    l[j] = bf16_rne(f[j] - bf16_f(hb));
  }
  ushort4 hv0 = {h[0], h[1], h[2], h[3]}, hv1 = {h[4], h[5], h[6], h[7]};
  ushort4 lv0 = {l[0], l[1], l[2], l[3]}, lv1 = {l[4], l[5], l[6], l[7]};
  ((ushort4*)hi)[i * 2] = hv0; ((ushort4*)hi)[i * 2 + 1] = hv1;
  ((ushort4*)lo)[i * 2] = lv0; ((ushort4*)lo)[i * 2 + 1] = lv1;
}

// ------ GEMM1 (2-term split MFMA): h1b[N,512](bf16) = x @ W1^T --------------
#define GLL(gp, lp) __builtin_amdgcn_global_load_lds( \
    (const __attribute__((address_space(1))) void*)(gp), \
    (__attribute__((address_space(3))) void*)(lp), 16, 0, 0)

// involutive chunk swizzle: spreads 64B-stride rows across all 8 bank groups
#define SWZ(c) ((c) ^ (((c) >> 3) & 3))

__global__ __launch_bounds__(256, 2) void gemm1_mfma(
    const unsigned short* __restrict__ Ab,
    const unsigned short* __restrict__ Bhi, const unsigned short* __restrict__ Blo,
    unsigned short* __restrict__ Cb)
{
  __shared__ unsigned short sA[128 * 32];
  __shared__ unsigned short sBhi[128 * 32], sBlo[128 * 32];
  int t = threadIdx.x;
  int bm = blockIdx.x, bn = blockIdx.y;
  int lane = t & 63, w = t >> 6;

  // staging: 512 16B-chunks per tile; LDS slot q holds tile-chunk SWZ(q)
  int slot0 = w * 128 + lane;
  int slot1 = slot0 + 64;
  int cb0 = w * 128, cb1 = w * 128 + 64;     // wave-uniform LDS base chunks
  int cs0 = SWZ(slot0), cs1 = SWZ(slot1);    // tile-chunk fetched by this lane
  int ar0 = bm * 128 + (cs0 >> 2); if (ar0 > Nn - 1) ar0 = Nn - 1;
  int ar1 = bm * 128 + (cs1 >> 2); if (ar1 > Nn - 1) ar1 = Nn - 1;
  int br0 = bn * 128 + (cs0 >> 2);
  int br1 = bn * 128 + (cs1 >> 2);
  size_t offA0 = (size_t)ar0 * IN_CH + (cs0 & 3) * 8;
  size_t offA1 = (size_t)ar1 * IN_CH + (cs1 & 3) * 8;
  size_t offB0 = (size_t)br0 * IN_CH + (cs0 & 3) * 8;
  size_t offB1 = (size_t)br1 * IN_CH + (cs1 & 3) * 8;

  int wm = (w >> 1) * 64, wn = (w & 1) * 64;
  int lr = lane & 15, kb = lane >> 4;

  f32x4 acc[4][4] = {};

  for (int k0 = 0; k0 < IN_CH; k0 += 32) {
    __syncthreads();                      // prev iter's LDS reads done
    GLL(Ab  + offA0 + k0, sA   + cb0 * 8);
    GLL(Ab  + offA1 + k0, sA   + cb1 * 8);
    GLL(Bhi + offB0 + k0, sBhi + cb0 * 8);
    GLL(Bhi + offB1 + k0, sBhi + cb1 * 8);
    GLL(Blo + offB0 + k0, sBlo + cb0 * 8);
    GLL(Blo + offB1 + k0, sBlo + cb1 * 8);
    __syncthreads();                      // loads landed

    bf16x8 ah[4], bh[4], bl[4];
#pragma unroll
    for (int i = 0; i < 4; i++) {
      int rca = (wm + i * 16 + lr) * 4 + kb;
      int sca = SWZ(rca);
      ah[i] = *(const bf16x8*)&sA[sca * 8];
      int rcb = (wn + i * 16 + lr) * 4 + kb;
      int scb = SWZ(rcb);
      bh[i] = *(const bf16x8*)&sBhi[scb * 8];
      bl[i] = *(const bf16x8*)&sBlo[scb * 8];
    }
#pragma unroll
    for (int i = 0; i < 4; i++)
#pragma unroll
      for (int j = 0; j < 4; j++) {
        acc[i][j] = __builtin_amdgcn_mfma_f32_16x16x32_bf16(ah[i], bh[j], acc[i][j], 0, 0, 0);
        acc[i][j] = __builtin_amdgcn_mfma_f32_16x16x32_bf16(ah[i], bl[j], acc[i][j], 0, 0, 0);
      }
  }

  int lq = lane >> 4;
#pragma unroll
  for (int i = 0; i < 4; i++) {
    int r0 = bm * 128 + wm + i * 16 + lq * 4;
#pragma unroll
    for (int j = 0; j < 4; j++) {
      int cc = bn * 128 + wn + j * 16 + lr;
#pragma unroll
      for (int q = 0; q < 4; q++) {
        int r = r0 + q;
        if (r < Nn) Cb[(size_t)r * C1 + cc] = bf16_rne(acc[i][j][q]);
      }
    }
  }
}

// ------------- per-(node,head) attention logits from bf16 h1 ----------------
__global__ __launch_bounds__(256) void logits1_kernel(
    const unsigned short* __restrict__ h1b, const float* __restrict__ att_s,
    const float* __restrict__ att_d, float* __restrict__ as1, float* __restrict__ ad1)
{
  int wave = threadIdx.x >> 6, lane = threadIdx.x & 63;
  int p = blockIdx.x * 4 + wave;            // pair index n*8+h
  if (p >= Nn * H1n) return;
  int n = p >> 3, h = p & 7;
  float v = bf16_f(h1b[(size_t)n * C1 + h * HIDn + lane]);
  float s = v * att_s[h * HIDn + lane];
  float d = v * att_d[h * HIDn + lane];
#pragma unroll
  for (int off = 32; off; off >>= 1) {
    s += __shfl_xor(s, off);
    d += __shfl_xor(d, off);
  }
  if (lane == 0) { as1[p] = s; ad1[p] = d; }
}

// --------------------------- CSR build by dst -------------------------------
__global__ void hist_kernel(const int* __restrict__ ei, int* __restrict__ cnt)
{
  int e = blockIdx.x * 256 + threadIdx.x;
  if (e >= EPn) return;
  int d = (e < En) ? ei[En + e] : (e - En);
  atomicAdd(&cnt[d], 1);
}

__global__ __launch_bounds__(1024) void scan_kernel(
    const int* __restrict__ cnt, int* __restrict__ row)
{
  __shared__ int wsum[16];
  int t = threadIdx.x;
  int base = t * 20;
  int v[20];
  int s = 0;
#pragma unroll
  for (int j = 0; j < 20; j++) {
    int i = base + j;
    int c = (i < Nn) ? cnt[i] : 0;
    v[j] = s;
    s += c;
  }
  int lane = t & 63, w = t >> 6;
  int incl = s;
#pragma unroll
  for (int off = 1; off < 64; off <<= 1) {
    int o = __shfl_up(incl, off);
    if (lane >= off) incl += o;
  }
  if (lane == 63) wsum[w] = incl;
  __syncthreads();
  if (w == 0) {
    int ws = (lane < 16) ? wsum[lane] : 0;
#pragma unroll
    for (int off = 1; off < 16; off <<= 1) {
      int o = __shfl_up(ws, off);
      if (lane >= off) ws += o;
    }
    if (lane < 16) wsum[lane] = ws;
  }
  __syncthreads();
  int excl = ((w > 0) ? wsum[w - 1] : 0) + incl - s;
#pragma unroll
  for (int j = 0; j < 20; j++) {
    int i = base + j;
    if (i < Nn) row[i] = excl + v[j];
  }
  if (t == 0) row[Nn] = EPn;
}

__global__ void scatter_kernel(const int* __restrict__ ei, const int* __restrict__ row,
                               int* __restrict__ cur, int* __restrict__ csr)
{
  int e = blockIdx.x * 256 + threadIdx.x;
  if (e >= EPn) return;
  int s, d;
  if (e < En) { s = ei[e]; d = ei[En + e]; }
  else        { s = e - En; d = e - En; }
  int pos = row[d] + atomicAdd(&cur[d], 1);
  csr[pos] = s;
}

// ----- per-dst softmax: m,z once per dst, then alpha[e][8] to global --------
// one wave per dst (4 dst per block); lanes stride edges
__global__ __launch_bounds__(256) void mza1_kernel(
    const int* __restrict__ row, const int* __restrict__ csr,
    const float* __restrict__ as1, const float* __restrict__ adv,
    float* __restrict__ alpha)
{
  int wv = threadIdx.x >> 6, lane = threadIdx.x & 63;
  int d = blockIdx.x * 4 + wv;               // grid = N/4 exactly
  int beg = row[d], end = row[d + 1];
  float4 ad0 = *(const float4*)&adv[d * 8];
  float4 ad1v = *(const float4*)&adv[d * 8 + 4];
  float adv8[8] = {ad0.x, ad0.y, ad0.z, ad0.w, ad1v.x, ad1v.y, ad1v.z, ad1v.w};

  float m[8], z[8];
#pragma unroll
  for (int h = 0; h < 8; h++) m[h] = -1e30f;
  for (int e = beg + lane; e < end; e += 64) {
    int s = csr[e];
    float4 a0 = *(const float4*)&as1[s * 8];
    float4 a1 = *(const float4*)&as1[s * 8 + 4];
    float av[8] = {a0.x, a0.y, a0.z, a0.w, a1.x, a1.y, a1.z, a1.w};
#pragma unroll
    for (int h = 0; h < 8; h++) {
      float v = av[h] + adv8[h];
      v = v >= 0.f ? v : NEG * v;
      m[h] = fmaxf(m[h], v);
    }
  }
#pragma unroll
  for (int h = 0; h < 8; h++)
#pragma unroll
    for (int off = 32; off; off >>= 1) m[h] = fmaxf(m[h], __shfl_xor(m[h], off));

#pragma unroll
  for (int h = 0; h < 8; h++) z[h] = 0.f;
  for (int e = beg + lane; e < end; e += 64) {
    int s = csr[e];
    float4 a0 = *(const float4*)&as1[s * 8];
    float4 a1 = *(const float4*)&as1[s * 8 + 4];
    float av[8] = {a0.x, a0.y, a0.z, a0.w, a1.x, a1.y, a1.z, a1.w};
#pragma unroll
    for (int h = 0; h < 8; h++) {
      float v = av[h] + adv8[h];
      v = v >= 0.f ? v : NEG * v;
      z[h] += __expf(v - m[h]);
    }
  }
#pragma unroll
  for (int h = 0; h < 8; h++)
#pragma unroll
    for (int off = 32; off; off >>= 1) z[h] += __shfl_xor(z[h], off);
  float rz[8];
#pragma unroll
  for (int h = 0; h < 8; h++) rz[h] = 1.f / z[h];

  for (int e = beg + lane; e < end; e += 64) {
    int s = csr[e];
    float4 a0 = *(const float4*)&as1[s * 8];
    float4 a1 = *(const float4*)&as1[s * 8 + 4];
    float av[8] = {a0.x, a0.y, a0.z, a0.w, a1.x, a1.y, a1.z, a1.w};
    float al[8];
#pragma unroll
    for (int h = 0; h < 8; h++) {
      float v = av[h] + adv8[h];
      v = v >= 0.f ? v : NEG * v;
      al[h] = __expf(v - m[h]) * rz[h];
    }
    float4 o0 = {al[0], al[1], al[2], al[3]};
    float4 o1 = {al[4], al[5], al[6], al[7]};
    *(float4*)&alpha[(size_t)e * 8] = o0;
    *(float4*)&alpha[(size_t)e * 8 + 4] = o1;
  }
}

// ----- layer-1 weighted gather (block per dst): pure alpha*h1 accumulate ----
// wave w takes edges e == w (mod 4); full 512-ch row at 16B/lane (8 ch/lane);
// alpha loaded directly from global (broadcast within 8-lane head groups).
// Cross-wave combine via stride-9-padded LDS (conflict-free), ONE barrier.
__global__ __launch_bounds__(256) void agg1_kernel(
    const int* __restrict__ row, const int* __restrict__ csr,
    const unsigned short* __restrict__ h1b, const float* __restrict__ alpha,
    const float* __restrict__ b1, unsigned short* __restrict__ outb)
{
  __shared__ float part[3][64 * 9];   // stride 9: 9 coprime 32 -> no conflicts

  int d = blockIdx.x;
  int beg = row[d], end = row[d + 1];
  int deg = end - beg;
  int t = threadIdx.x, lane = t & 63, w = t >> 6;
  int hq = lane >> 3;                 // this lane's head (8 ch/lane)
  size_t chb = (size_t)8 * lane;

  int nj = (deg > w) ? ((deg - w + 3) >> 2) : 0;

  float a0 = 0.f, a1 = 0.f, a2 = 0.f, a3 = 0.f;
  float a4 = 0.f, a5 = 0.f, a6 = 0.f, a7 = 0.f;
#pragma unroll 2
  for (int j = 0; j < nj; j++) {
    int e = beg + w + 4 * j;
    float al = alpha[(size_t)e * 8 + hq];
    int s = csr[e];
    uint4 u = *(const uint4*)&h1b[(size_t)s * C1 + chb];
    a0 = fmaf(al, __uint_as_float(u.x << 16), a0);
    a1 = fmaf(al, __uint_as_float(u.x & 0xffff0000u), a1);
    a2 = fmaf(al, __uint_as_float(u.y << 16), a2);
    a3 = fmaf(al, __uint_as_float(u.y & 0xffff0000u), a3);
    a4 = fmaf(al, __uint_as_float(u.z << 16), a4);
    a5 = fmaf(al, __uint_as_float(u.z & 0xffff0000u), a5);
    a6 = fmaf(al, __uint_as_float(u.w << 16), a6);
    a7 = fmaf(al, __uint_as_float(u.w & 0xffff0000u), a7);
  }

  if (w) {
    float* ps = &part[w - 1][lane * 9];
    ps[0] = a0; ps[1] = a1; ps[2] = a2; ps[3] = a3;
    ps[4] = a4; ps[5] = a5; ps[6] = a6; ps[7] = a7;
  }
  __syncthreads();
  if (w == 0) {
#pragma unroll
    for (int q = 0; q < 3; q++) {
      const float* ps = &part[q][lane * 9];
      a0 += ps[0]; a1 += ps[1]; a2 += ps[2]; a3 += ps[3];
      a4 += ps[4]; a5 += ps[5]; a6 += ps[6]; a7 += ps[7];
    }
    float4 b0 = *(const float4*)&b1[chb];
    float4 b4 = *(const float4*)&b1[chb + 4];
    float o[8] = {a0 + b0.x, a1 + b0.y, a2 + b0.z, a3 + b0.w,
                  a4 + b4.x, a5 + b4.y, a6 + b4.z, a7 + b4.w};
    unsigned short r[8];
#pragma unroll
    for (int i = 0; i < 8; i++) r[i] = bf16_rne(o[i] > 0.f ? o[i] : 0.f);
    ushort4 r0 = {r[0], r[1], r[2], r[3]}, r4 = {r[4], r[5], r[6], r[7]};
    *(ushort4*)&outb[(size_t)d * C1 + chb] = r0;
    *(ushort4*)&outb[(size_t)d * C1 + chb + 4] = r4;
  }
}

// --------- layer-2 transform: h2[N,16] = relu1b @ W2^T; a_s2, a_d2 ----------
__global__ __launch_bounds__(256) void l2_kernel(
    const unsigned short* __restrict__ in, const float* __restrict__ W2,
    const float* __restrict__ att_s, const float* __restrict__ att_d,
    float* __restrict__ h2, float* __restrict__ as2, float* __restrict__ ad2)
{
  __shared__ float W2s[OUT_CH * 512];
  int t = threadIdx.x;
  for (int i = t * 4; i < OUT_CH * 512; i += 1024)
    *(float4*)&W2s[i] = *(const float4*)&W2[i];
  __syncthreads();
  int wave = t >> 6, lane = t & 63;
  int n = blockIdx.x * 4 + wave;   // grid = N/4 exactly
  const unsigned short* xr = in + (size_t)n * 512;
  float acc[16] = {};
  for (int k = lane; k < 512; k += 64) {
    float xv = bf16_f(xr[k]);
#pragma unroll
    for (int j = 0; j < 16; j++) acc[j] = fmaf(xv, W2s[j * 512 + k], acc[j]);
  }
#pragma unroll
  for (int j = 0; j < 16; j++)
#pragma unroll
    for (int off = 32; off; off >>= 1) acc[j] += __shfl_xor(acc[j], off);
  if (lane == 0) {
    float s = 0.f, dd = 0.f;
#pragma unroll
    for (int j = 0; j < 16; j++) {
      h2[(size_t)n * 16 + j] = acc[j];
      s  = fmaf(acc[j], att_s[j], s);
      dd = fmaf(acc[j], att_d[j], dd);
    }
    as2[n] = s; ad2[n] = dd;
  }
}

// ------- layer-2 softmax + aggregate (one wave per dst), fused +b2 ----------
__global__ __launch_bounds__(256) void agg2_kernel(
    const int* __restrict__ row, const int* __restrict__ csr,
    const float* __restrict__ h2, const float* __restrict__ as2,
    const float* __restrict__ ad2, const float* __restrict__ b2,
    float* __restrict__ out)
{
  int wave = threadIdx.x >> 6, lane = threadIdx.x & 63;
  int d = blockIdx.x * 4 + wave;   // grid = N/4 exactly
  int beg = row[d], end = row[d + 1];
  float add = ad2[d];

  float m = -1e30f;
  for (int e = beg + lane; e < end; e += 64) {
    float v = as2[csr[e]] + add;
    v = (v >= 0.f) ? v : NEG * v;
    m = fmaxf(m, v);
  }
#pragma unroll
  for (int off = 32; off; off >>= 1) m = fmaxf(m, __shfl_xor(m, off));
  float z = 0.f;
  for (int e = beg + lane; e < end; e += 64) {
    float v = as2[csr[e]] + add;
    v = (v >= 0.f) ? v : NEG * v;
    z += __expf(v - m);
  }
#pragma unroll
  for (int off = 32; off; off >>= 1) z += __shfl_xor(z, off);

  int c = lane & 15;
  float acc = 0.f;
  for (int e = beg + (lane >> 4); e < end; e += 4) {
    int s = csr[e];
    float v = as2[s] + add;
    v = (v >= 0.f) ? v : NEG * v;
    float al = __expf(v - m) / z;
    acc = fmaf(al, h2[(size_t)s * 16 + c], acc);
  }
  acc += __shfl_xor(acc, 16);
  acc += __shfl_xor(acc, 32);
  if (lane < 16) out[(size_t)d * 16 + lane] = acc + b2[lane];
}

extern "C" void kernel_launch(void* const* d_in, const int* in_sizes, int n_in,
                              void* d_out, int out_size, void* d_ws, size_t ws_size,
                              hipStream_t stream)
{
  const float* x    = (const float*)d_in[0];
  const int*   ei   = (const int*)d_in[1];
  const float* W1   = (const float*)d_in[2];
  const float* asv1 = (const float*)d_in[3];
  const float* adv1 = (const float*)d_in[4];
  const float* b1   = (const float*)d_in[5];
  const float* W2   = (const float*)d_in[6];
  const float* asv2 = (const float*)d_in[7];
  const float* adv2 = (const float*)d_in[8];
  const float* b2   = (const float*)d_in[9];
  float* out = (float*)d_out;

  // workspace layout (16B-aligned regions), ~58.8 MB total
  unsigned short* h1b    = (unsigned short*)d_ws;             // N*512 bf16
  unsigned short* relu1b = h1b + (size_t)Nn * C1;             // N*512 bf16 (aliased x_b pre-agg1)
  float* alpha = (float*)(relu1b + (size_t)Nn * C1);          // EPn*8 f32 (aliased W splits pre-mza1)
  float* as1   = alpha + (size_t)EPn * 8;                     // N*8
  float* ad1   = as1 + (size_t)Nn * H1n;                      // N*8
  float* h2    = ad1 + (size_t)Nn * H1n;                      // N*16
  float* as2   = h2 + (size_t)Nn * OUT_CH;                    // N
  float* ad2   = as2 + Nn;                                    // N
  int* csr  = (int*)(ad2 + Nn);                               // E+N
  int* cnt  = csr + EPn;                                      // N
  int* rowp = cnt + Nn;                                       // N+1
  int* cur  = rowp + Nn + 1;                                  // N

  unsigned short* x_b  = (unsigned short*)relu1b;             // N*512 bf16
  unsigned short* w_hi = (unsigned short*)alpha;              // 512*512 bf16
  unsigned short* w_lo = w_hi + (size_t)C1 * IN_CH;           // 512*512 bf16

  hipMemsetAsync(cnt, 0, Nn * sizeof(int), stream);
  hipMemsetAsync(cur, 0, Nn * sizeof(int), stream);

  cvt_kernel<<<(Nn * IN_CH / 8 + 255) / 256, 256, 0, stream>>>(x, x_b, Nn * IN_CH / 8);
  split_kernel<<<(C1 * IN_CH / 8 + 255) / 256, 256, 0, stream>>>(W1, w_hi, w_lo, C1 * IN_CH / 8);

  dim3 g1(157, 4);
  gemm1_mfma<<<g1, 256, 0, stream>>>(x_b, w_hi, w_lo, h1b);

  logits1_kernel<<<(Nn * H1n) / 4, 256, 0, stream>>>(h1b, asv1, adv1, as1, ad1);
  hist_kernel<<<(EPn + 255) / 256, 256, 0, stream>>>(ei, cnt);
  scan_kernel<<<1, 1024, 0, stream>>>(cnt, rowp);
  scatter_kernel<<<(EPn + 255) / 256, 256, 0, stream>>>(ei, rowp, cur, csr);
  mza1_kernel<<<Nn / 4, 256, 0, stream>>>(rowp, csr, as1, ad1, alpha);        // overwrites w_hi/w_lo (gemm done)
  agg1_kernel<<<Nn, 256, 0, stream>>>(rowp, csr, h1b, alpha, b1, relu1b);     // overwrites x_b (gemm done)
  l2_kernel<<<Nn / 4, 256, 0, stream>>>(relu1b, W2, asv2, adv2, h2, as2, ad2);
  agg2_kernel<<<Nn / 4, 256, 0, stream>>>(rowp, csr, h2, as2, ad2, b2, out);
}

// Round 8
// 230.191 us; speedup vs baseline: 1.2145x; 1.1043x over previous
//
#include <hip/hip_runtime.h>

#define Nn     20000
#define IN_CH  512
#define C1     512      // H1*HID
#define H1n    8
#define HIDn   64
#define OUT_CH 16
#define En     320000
#define EPn    340000   // E + N self-loops
#define NEG    0.2f

typedef __attribute__((ext_vector_type(8))) short bf16x8;
typedef __attribute__((ext_vector_type(4))) float f32x4;

// ---------------- fp32 -> bf16 helpers (RNE) --------------------------------
__device__ inline unsigned short bf16_rne(float f) {
  unsigned int u = __float_as_uint(f);
  return (unsigned short)((u + 0x7fffu + ((u >> 16) & 1u)) >> 16);
}
__device__ inline float bf16_f(unsigned short u) {
  return __uint_as_float(((unsigned int)u) << 16);
}

// x and W -> bf16 in one launch
#define NX8 (Nn * IN_CH / 8)
#define NW8 (C1 * IN_CH / 8)
__global__ __launch_bounds__(256) void cvt2_kernel(
    const float* __restrict__ x, unsigned short* __restrict__ xb,
    const float* __restrict__ W, unsigned short* __restrict__ wb)
{
  int i = blockIdx.x * 256 + threadIdx.x;
  const float* in; unsigned short* ob; int idx;
  if (i < NX8) { in = x; ob = xb; idx = i; }
  else if (i < NX8 + NW8) { in = W; ob = wb; idx = i - NX8; }
  else return;
  float4 f0 = ((const float4*)in)[idx * 2];
  float4 f1 = ((const float4*)in)[idx * 2 + 1];
  float f[8] = {f0.x, f0.y, f0.z, f0.w, f1.x, f1.y, f1.z, f1.w};
  unsigned short h[8];
#pragma unroll
  for (int j = 0; j < 8; j++) h[j] = bf16_rne(f[j]);
  ushort4 hv0 = {h[0], h[1], h[2], h[3]}, hv1 = {h[4], h[5], h[6], h[7]};
  ((ushort4*)ob)[idx * 2] = hv0; ((ushort4*)ob)[idx * 2 + 1] = hv1;
}

// ------ GEMM1 (bf16 MFMA): h1b[N,512](bf16) = x @ W1^T ----------------------
#define GLL(gp, lp) __builtin_amdgcn_global_load_lds( \
    (const __attribute__((address_space(1))) void*)(gp), \
    (__attribute__((address_space(3))) void*)(lp), 16, 0, 0)

// involutive chunk swizzle: spreads 64B-stride rows across all 8 bank groups
#define SWZ(c) ((c) ^ (((c) >> 3) & 3))

__global__ __launch_bounds__(256, 2) void gemm1_mfma(
    const unsigned short* __restrict__ Ab, const unsigned short* __restrict__ Bb,
    unsigned short* __restrict__ Cb)
{
  __shared__ unsigned short sA[128 * 32], sB[128 * 32];
  int t = threadIdx.x;
  int bm = blockIdx.x, bn = blockIdx.y;
  int lane = t & 63, w = t >> 6;

  // staging: 512 16B-chunks per tile; LDS slot q holds tile-chunk SWZ(q)
  int slot0 = w * 128 + lane;
  int slot1 = slot0 + 64;
  int cb0 = w * 128, cb1 = w * 128 + 64;     // wave-uniform LDS base chunks
  int cs0 = SWZ(slot0), cs1 = SWZ(slot1);    // tile-chunk fetched by this lane
  int ar0 = bm * 128 + (cs0 >> 2); if (ar0 > Nn - 1) ar0 = Nn - 1;
  int ar1 = bm * 128 + (cs1 >> 2); if (ar1 > Nn - 1) ar1 = Nn - 1;
  int br0 = bn * 128 + (cs0 >> 2);
  int br1 = bn * 128 + (cs1 >> 2);
  size_t offA0 = (size_t)ar0 * IN_CH + (cs0 & 3) * 8;
  size_t offA1 = (size_t)ar1 * IN_CH + (cs1 & 3) * 8;
  size_t offB0 = (size_t)br0 * IN_CH + (cs0 & 3) * 8;
  size_t offB1 = (size_t)br1 * IN_CH + (cs1 & 3) * 8;

  int wm = (w >> 1) * 64, wn = (w & 1) * 64;
  int lr = lane & 15, kb = lane >> 4;

  f32x4 acc[4][4] = {};

  for (int k0 = 0; k0 < IN_CH; k0 += 32) {
    __syncthreads();                      // prev iter's LDS reads done
    GLL(Ab + offA0 + k0, sA + cb0 * 8);
    GLL(Ab + offA1 + k0, sA + cb1 * 8);
    GLL(Bb + offB0 + k0, sB + cb0 * 8);
    GLL(Bb + offB1 + k0, sB + cb1 * 8);
    __syncthreads();                      // loads landed

    bf16x8 ah[4], bh[4];
#pragma unroll
    for (int i = 0; i < 4; i++) {
      int rca = (wm + i * 16 + lr) * 4 + kb;
      ah[i] = *(const bf16x8*)&sA[SWZ(rca) * 8];
      int rcb = (wn + i * 16 + lr) * 4 + kb;
      bh[i] = *(const bf16x8*)&sB[SWZ(rcb) * 8];
    }
#pragma unroll
    for (int i = 0; i < 4; i++)
#pragma unroll
      for (int j = 0; j < 4; j++)
        acc[i][j] = __builtin_amdgcn_mfma_f32_16x16x32_bf16(ah[i], bh[j], acc[i][j], 0, 0, 0);
  }

  int lq = lane >> 4;
#pragma unroll
  for (int i = 0; i < 4; i++) {
    int r0 = bm * 128 + wm + i * 16 + lq * 4;
#pragma unroll
    for (int j = 0; j < 4; j++) {
      int cc = bn * 128 + wn + j * 16 + lr;
#pragma unroll
      for (int q = 0; q < 4; q++) {
        int r = r0 + q;
        if (r < Nn) Cb[(size_t)r * C1 + cc] = bf16_rne(acc[i][j][q]);
      }
    }
  }
}

// ------------- per-(node,head) attention logits from bf16 h1 ----------------
__global__ __launch_bounds__(256) void logits1_kernel(
    const unsigned short* __restrict__ h1b, const float* __restrict__ att_s,
    const float* __restrict__ att_d, float* __restrict__ as1, float* __restrict__ ad1)
{
  int wave = threadIdx.x >> 6, lane = threadIdx.x & 63;
  int p = blockIdx.x * 4 + wave;            // pair index n*8+h
  if (p >= Nn * H1n) return;
  int n = p >> 3, h = p & 7;
  float v = bf16_f(h1b[(size_t)n * C1 + h * HIDn + lane]);
  float s = v * att_s[h * HIDn + lane];
  float d = v * att_d[h * HIDn + lane];
#pragma unroll
  for (int off = 32; off; off >>= 1) {
    s += __shfl_xor(s, off);
    d += __shfl_xor(d, off);
  }
  if (lane == 0) { as1[p] = s; ad1[p] = d; }
}

// --------------------------- CSR build by dst -------------------------------
__global__ void hist_kernel(const int* __restrict__ ei, int* __restrict__ cnt)
{
  int e = blockIdx.x * 256 + threadIdx.x;
  if (e >= EPn) return;
  int d = (e < En) ? ei[En + e] : (e - En);
  atomicAdd(&cnt[d], 1);
}

__global__ __launch_bounds__(1024) void scan_kernel(
    const int* __restrict__ cnt, int* __restrict__ row)
{
  __shared__ int wsum[16];
  int t = threadIdx.x;
  int base = t * 20;
  int v[20];
  int s = 0;
#pragma unroll
  for (int j = 0; j < 20; j++) {
    int i = base + j;
    int c = (i < Nn) ? cnt[i] : 0;
    v[j] = s;
    s += c;
  }
  int lane = t & 63, w = t >> 6;
  int incl = s;
#pragma unroll
  for (int off = 1; off < 64; off <<= 1) {
    int o = __shfl_up(incl, off);
    if (lane >= off) incl += o;
  }
  if (lane == 63) wsum[w] = incl;
  __syncthreads();
  if (w == 0) {
    int ws = (lane < 16) ? wsum[lane] : 0;
#pragma unroll
    for (int off = 1; off < 16; off <<= 1) {
      int o = __shfl_up(ws, off);
      if (lane >= off) ws += o;
    }
    if (lane < 16) wsum[lane] = ws;
  }
  __syncthreads();
  int excl = ((w > 0) ? wsum[w - 1] : 0) + incl - s;
#pragma unroll
  for (int j = 0; j < 20; j++) {
    int i = base + j;
    if (i < Nn) row[i] = excl + v[j];
  }
  if (t == 0) row[Nn] = EPn;
}

__global__ void scatter_kernel(const int* __restrict__ ei, const int* __restrict__ row,
                               int* __restrict__ cur, int* __restrict__ csr)
{
  int e = blockIdx.x * 256 + threadIdx.x;
  if (e >= EPn) return;
  int s, d;
  if (e < En) { s = ei[e]; d = ei[En + e]; }
  else        { s = e - En; d = e - En; }
  int pos = row[d] + atomicAdd(&cur[d], 1);
  csr[pos] = s;
}

// ----- layer-1 fused softmax + weighted gather (block per dst) --------------
// Softmax prologue, (edge,head)-parallel: thread t owns head t&7, edges stride
// 32; per-(edge,head) work done once.  Reduce: shfl_xor(8/16/32) within wave +
// write-once red[4][8] + barrier.  Gather: wave w takes edges e==w (mod 4),
// full 512-ch row at 16B/lane (8 ch/lane, head lane>>3), alpha computed
// inline per lane.  Combine via stride-9 LDS, one barrier.  All cross-wave
// communication is write-once -> barrier -> read (replay-deterministic).
__global__ __launch_bounds__(256) void agg1_kernel(
    const int* __restrict__ row, const int* __restrict__ csr,
    const unsigned short* __restrict__ h1b, const float* __restrict__ as1,
    const float* __restrict__ adv, const float* __restrict__ b1,
    unsigned short* __restrict__ outb)
{
  __shared__ float redm[4][8], redz[4][8];
  __shared__ float fm[8], frz[8];
  __shared__ float part[3][64 * 9];   // stride 9: conflict-free combine

  int d = blockIdx.x;
  int beg = row[d], end = row[d + 1];
  int deg = end - beg;
  int t = threadIdx.x, lane = t & 63, w = t >> 6;
  int h8 = t & 7;                     // head this thread handles in m/z phases
  int es = t >> 3;                    // edge start (0..31), stride 32
  float adA = adv[d * 8 + h8];

  // phase A: per-head max
  float mp = -1e30f;
  for (int j = es; j < deg; j += 32) {
    int s = csr[beg + j];
    float v = as1[s * 8 + h8] + adA;
    v = v >= 0.f ? v : NEG * v;
    mp = fmaxf(mp, v);
  }
  mp = fmaxf(mp, __shfl_xor(mp, 8));
  mp = fmaxf(mp, __shfl_xor(mp, 16));
  mp = fmaxf(mp, __shfl_xor(mp, 32));
  if (lane < 8) redm[w][lane] = mp;
  __syncthreads();
  float mf = fmaxf(fmaxf(redm[0][h8], redm[1][h8]),
                   fmaxf(redm[2][h8], redm[3][h8]));

  // phase B: per-head denominator
  float zp = 0.f;
  for (int j = es; j < deg; j += 32) {
    int s = csr[beg + j];
    float v = as1[s * 8 + h8] + adA;
    v = v >= 0.f ? v : NEG * v;
    zp += __expf(v - mf);
  }
  zp += __shfl_xor(zp, 8);
  zp += __shfl_xor(zp, 16);
  zp += __shfl_xor(zp, 32);
  if (lane < 8) redz[w][lane] = zp;
  __syncthreads();
  if (t < 8) {
    float zf = redz[0][t] + redz[1][t] + redz[2][t] + redz[3][t];
    fm[t] = mf;                        // t<8 => h8==t
    frz[t] = 1.f / zf;
  }
  __syncthreads();

  // gather phase: wave w, edges e = beg + w + 4j; 8 channels/lane
  int hq = lane >> 3;
  float mH = fm[hq], rzH = frz[hq];
  float adH = adv[d * 8 + hq];
  size_t chb = (size_t)8 * lane;
  int nj = (deg > w) ? ((deg - w + 3) >> 2) : 0;

  float a0 = 0.f, a1 = 0.f, a2 = 0.f, a3 = 0.f;
  float a4 = 0.f, a5 = 0.f, a6 = 0.f, a7 = 0.f;
#pragma unroll 2
  for (int j = 0; j < nj; j++) {
    int e = beg + w + 4 * j;
    int s = csr[e];
    float v = as1[s * 8 + hq] + adH;
    v = v >= 0.f ? v : NEG * v;
    float al = __expf(v - mH) * rzH;
    uint4 u = *(const uint4*)&h1b[(size_t)s * C1 + chb];
    a0 = fmaf(al, __uint_as_float(u.x << 16), a0);
    a1 = fmaf(al, __uint_as_float(u.x & 0xffff0000u), a1);
    a2 = fmaf(al, __uint_as_float(u.y << 16), a2);
    a3 = fmaf(al, __uint_as_float(u.y & 0xffff0000u), a3);
    a4 = fmaf(al, __uint_as_float(u.z << 16), a4);
    a5 = fmaf(al, __uint_as_float(u.z & 0xffff0000u), a5);
    a6 = fmaf(al, __uint_as_float(u.w << 16), a6);
    a7 = fmaf(al, __uint_as_float(u.w & 0xffff0000u), a7);
  }

  if (w) {
    float* ps = &part[w - 1][lane * 9];
    ps[0] = a0; ps[1] = a1; ps[2] = a2; ps[3] = a3;
    ps[4] = a4; ps[5] = a5; ps[6] = a6; ps[7] = a7;
  }
  __syncthreads();
  if (w == 0) {
#pragma unroll
    for (int q = 0; q < 3; q++) {
      const float* ps = &part[q][lane * 9];
      a0 += ps[0]; a1 += ps[1]; a2 += ps[2]; a3 += ps[3];
      a4 += ps[4]; a5 += ps[5]; a6 += ps[6]; a7 += ps[7];
    }
    float4 b0 = *(const float4*)&b1[chb];
    float4 b4 = *(const float4*)&b1[chb + 4];
    float o[8] = {a0 + b0.x, a1 + b0.y, a2 + b0.z, a3 + b0.w,
                  a4 + b4.x, a5 + b4.y, a6 + b4.z, a7 + b4.w};
    unsigned short r[8];
#pragma unroll
    for (int i = 0; i < 8; i++) r[i] = bf16_rne(o[i] > 0.f ? o[i] : 0.f);
    ushort4 r0 = {r[0], r[1], r[2], r[3]}, r4 = {r[4], r[5], r[6], r[7]};
    *(ushort4*)&outb[(size_t)d * C1 + chb] = r0;
    *(ushort4*)&outb[(size_t)d * C1 + chb + 4] = r4;
  }
}

// --------- layer-2 transform: h2[N,16] = relu1b @ W2^T; a_s2, a_d2 ----------
__global__ __launch_bounds__(256) void l2_kernel(
    const unsigned short* __restrict__ in, const float* __restrict__ W2,
    const float* __restrict__ att_s, const float* __restrict__ att_d,
    float* __restrict__ h2, float* __restrict__ as2, float* __restrict__ ad2)
{
  __shared__ float W2s[OUT_CH * 512];
  int t = threadIdx.x;
  for (int i = t * 4; i < OUT_CH * 512; i += 1024)
    *(float4*)&W2s[i] = *(const float4*)&W2[i];
  __syncthreads();
  int wave = t >> 6, lane = t & 63;
  int n = blockIdx.x * 4 + wave;   // grid = N/4 exactly
  const unsigned short* xr = in + (size_t)n * 512;
  float acc[16] = {};
  for (int k = lane; k < 512; k += 64) {
    float xv = bf16_f(xr[k]);
#pragma unroll
    for (int j = 0; j < 16; j++) acc[j] = fmaf(xv, W2s[j * 512 + k], acc[j]);
  }
#pragma unroll
  for (int j = 0; j < 16; j++)
#pragma unroll
    for (int off = 32; off; off >>= 1) acc[j] += __shfl_xor(acc[j], off);
  if (lane == 0) {
    float s = 0.f, dd = 0.f;
#pragma unroll
    for (int j = 0; j < 16; j++) {
      h2[(size_t)n * 16 + j] = acc[j];
      s  = fmaf(acc[j], att_s[j], s);
      dd = fmaf(acc[j], att_d[j], dd);
    }
    as2[n] = s; ad2[n] = dd;
  }
}

// ------- layer-2 softmax + aggregate (one wave per dst), fused +b2 ----------
__global__ __launch_bounds__(256) void agg2_kernel(
    const int* __restrict__ row, const int* __restrict__ csr,
    const float* __restrict__ h2, const float* __restrict__ as2,
    const float* __restrict__ ad2, const float* __restrict__ b2,
    float* __restrict__ out)
{
  int wave = threadIdx.x >> 6, lane = threadIdx.x & 63;
  int d = blockIdx.x * 4 + wave;   // grid = N/4 exactly
  int beg = row[d], end = row[d + 1];
  float add = ad2[d];

  float m = -1e30f;
  for (int e = beg + lane; e < end; e += 64) {
    float v = as2[csr[e]] + add;
    v = (v >= 0.f) ? v : NEG * v;
    m = fmaxf(m, v);
  }
#pragma unroll
  for (int off = 32; off; off >>= 1) m = fmaxf(m, __shfl_xor(m, off));
  float z = 0.f;
  for (int e = beg + lane; e < end; e += 64) {
    float v = as2[csr[e]] + add;
    v = (v >= 0.f) ? v : NEG * v;
    z += __expf(v - m);
  }
#pragma unroll
  for (int off = 32; off; off >>= 1) z += __shfl_xor(z, off);

  int c = lane & 15;
  float acc = 0.f;
  for (int e = beg + (lane >> 4); e < end; e += 4) {
    int s = csr[e];
    float v = as2[s] + add;
    v = (v >= 0.f) ? v : NEG * v;
    float al = __expf(v - m) / z;
    acc = fmaf(al, h2[(size_t)s * 16 + c], acc);
  }
  acc += __shfl_xor(acc, 16);
  acc += __shfl_xor(acc, 32);
  if (lane < 16) out[(size_t)d * 16 + lane] = acc + b2[lane];
}

extern "C" void kernel_launch(void* const* d_in, const int* in_sizes, int n_in,
                              void* d_out, int out_size, void* d_ws, size_t ws_size,
                              hipStream_t stream)
{
  const float* x    = (const float*)d_in[0];
  const int*   ei   = (const int*)d_in[1];
  const float* W1   = (const float*)d_in[2];
  const float* asv1 = (const float*)d_in[3];
  const float* adv1 = (const float*)d_in[4];
  const float* b1   = (const float*)d_in[5];
  const float* W2   = (const float*)d_in[6];
  const float* asv2 = (const float*)d_in[7];
  const float* adv2 = (const float*)d_in[8];
  const float* b2   = (const float*)d_in[9];
  float* out = (float*)d_out;

  // workspace layout (16B-aligned regions), ~46 MB total
  unsigned short* h1b    = (unsigned short*)d_ws;             // N*512 bf16
  unsigned short* relu1b = h1b + (size_t)Nn * C1;             // N*512 bf16 (aliased x_b pre-agg1)
  unsigned short* w_b    = relu1b + (size_t)Nn * C1;          // 512*512 bf16
  float* as1   = (float*)(w_b + (size_t)C1 * IN_CH);          // N*8
  float* ad1   = as1 + (size_t)Nn * H1n;                      // N*8
  float* h2    = ad1 + (size_t)Nn * H1n;                      // N*16
  float* as2   = h2 + (size_t)Nn * OUT_CH;                    // N
  float* ad2   = as2 + Nn;                                    // N
  int* csr  = (int*)(ad2 + Nn);                               // E+N
  int* cnt  = csr + EPn;                                      // N
  int* rowp = cnt + Nn;                                       // N+1
  int* cur  = rowp + Nn + 1;                                  // N

  unsigned short* x_b = (unsigned short*)relu1b;              // N*512 bf16

  hipMemsetAsync(cnt, 0, Nn * sizeof(int), stream);
  hipMemsetAsync(cur, 0, Nn * sizeof(int), stream);

  cvt2_kernel<<<(NX8 + NW8 + 255) / 256, 256, 0, stream>>>(x, x_b, W1, w_b);

  dim3 g1(157, 4);
  gemm1_mfma<<<g1, 256, 0, stream>>>(x_b, w_b, h1b);

  logits1_kernel<<<(Nn * H1n) / 4, 256, 0, stream>>>(h1b, asv1, adv1, as1, ad1);
  hist_kernel<<<(EPn + 255) / 256, 256, 0, stream>>>(ei, cnt);
  scan_kernel<<<1, 1024, 0, stream>>>(cnt, rowp);
  scatter_kernel<<<(EPn + 255) / 256, 256, 0, stream>>>(ei, rowp, cur, csr);
  agg1_kernel<<<Nn, 256, 0, stream>>>(rowp, csr, h1b, as1, ad1, b1, relu1b);  // overwrites x_b (gemm done)
  l2_kernel<<<Nn / 4, 256, 0, stream>>>(relu1b, W2, asv2, adv2, h2, as2, ad2);
  agg2_kernel<<<Nn / 4, 256, 0, stream>>>(rowp, csr, h2, as2, ad2, b2, out);
}

// Round 9
// 217.626 us; speedup vs baseline: 1.2846x; 1.0577x over previous
//
#include <hip/hip_runtime.h>

#define Nn     20000
#define IN_CH  512
#define C1     512      // H1*HID
#define H1n    8
#define HIDn   64
#define OUT_CH 16
#define En     320000
#define EPn    340000   // E + N self-loops
#define NEG    0.2f

typedef __attribute__((ext_vector_type(8))) short bf16x8;
typedef __attribute__((ext_vector_type(4))) float f32x4;

// ---------------- fp32 -> bf16 helpers (RNE) --------------------------------
__device__ inline unsigned short bf16_rne(float f) {
  unsigned int u = __float_as_uint(f);
  return (unsigned short)((u + 0x7fffu + ((u >> 16) & 1u)) >> 16);
}
__device__ inline float bf16_f(unsigned short u) {
  return __uint_as_float(((unsigned int)u) << 16);
}

// x and W -> bf16 in one launch
#define NX8 (Nn * IN_CH / 8)
#define NW8 (C1 * IN_CH / 8)
__global__ __launch_bounds__(256) void cvt2_kernel(
    const float* __restrict__ x, unsigned short* __restrict__ xb,
    const float* __restrict__ W, unsigned short* __restrict__ wb)
{
  int i = blockIdx.x * 256 + threadIdx.x;
  const float* in; unsigned short* ob; int idx;
  if (i < NX8) { in = x; ob = xb; idx = i; }
  else if (i < NX8 + NW8) { in = W; ob = wb; idx = i - NX8; }
  else return;
  float4 f0 = ((const float4*)in)[idx * 2];
  float4 f1 = ((const float4*)in)[idx * 2 + 1];
  float f[8] = {f0.x, f0.y, f0.z, f0.w, f1.x, f1.y, f1.z, f1.w};
  unsigned short h[8];
#pragma unroll
  for (int j = 0; j < 8; j++) h[j] = bf16_rne(f[j]);
  ushort4 hv0 = {h[0], h[1], h[2], h[3]}, hv1 = {h[4], h[5], h[6], h[7]};
  ((ushort4*)ob)[idx * 2] = hv0; ((ushort4*)ob)[idx * 2 + 1] = hv1;
}

// ------ GEMM1 (bf16 MFMA): h1b[N,512](bf16) = x @ W1^T ----------------------
#define GLL(gp, lp) __builtin_amdgcn_global_load_lds( \
    (const __attribute__((address_space(1))) void*)(gp), \
    (__attribute__((address_space(3))) void*)(lp), 16, 0, 0)

// involutive chunk swizzle: spreads 64B-stride rows across all 8 bank groups
#define SWZ(c) ((c) ^ (((c) >> 3) & 3))

__global__ __launch_bounds__(256, 2) void gemm1_mfma(
    const unsigned short* __restrict__ Ab, const unsigned short* __restrict__ Bb,
    unsigned short* __restrict__ Cb)
{
  __shared__ unsigned short sA[128 * 32], sB[128 * 32];
  int t = threadIdx.x;
  int bm = blockIdx.x, bn = blockIdx.y;
  int lane = t & 63, w = t >> 6;

  // staging: 512 16B-chunks per tile; LDS slot q holds tile-chunk SWZ(q)
  int slot0 = w * 128 + lane;
  int slot1 = slot0 + 64;
  int cb0 = w * 128, cb1 = w * 128 + 64;     // wave-uniform LDS base chunks
  int cs0 = SWZ(slot0), cs1 = SWZ(slot1);    // tile-chunk fetched by this lane
  int ar0 = bm * 128 + (cs0 >> 2); if (ar0 > Nn - 1) ar0 = Nn - 1;
  int ar1 = bm * 128 + (cs1 >> 2); if (ar1 > Nn - 1) ar1 = Nn - 1;
  int br0 = bn * 128 + (cs0 >> 2);
  int br1 = bn * 128 + (cs1 >> 2);
  size_t offA0 = (size_t)ar0 * IN_CH + (cs0 & 3) * 8;
  size_t offA1 = (size_t)ar1 * IN_CH + (cs1 & 3) * 8;
  size_t offB0 = (size_t)br0 * IN_CH + (cs0 & 3) * 8;
  size_t offB1 = (size_t)br1 * IN_CH + (cs1 & 3) * 8;

  int wm = (w >> 1) * 64, wn = (w & 1) * 64;
  int lr = lane & 15, kb = lane >> 4;

  f32x4 acc[4][4] = {};

  for (int k0 = 0; k0 < IN_CH; k0 += 32) {
    __syncthreads();                      // prev iter's LDS reads done
    GLL(Ab + offA0 + k0, sA + cb0 * 8);
    GLL(Ab + offA1 + k0, sA + cb1 * 8);
    GLL(Bb + offB0 + k0, sB + cb0 * 8);
    GLL(Bb + offB1 + k0, sB + cb1 * 8);
    __syncthreads();                      // loads landed

    bf16x8 ah[4], bh[4];
#pragma unroll
    for (int i = 0; i < 4; i++) {
      int rca = (wm + i * 16 + lr) * 4 + kb;
      ah[i] = *(const bf16x8*)&sA[SWZ(rca) * 8];
      int rcb = (wn + i * 16 + lr) * 4 + kb;
      bh[i] = *(const bf16x8*)&sB[SWZ(rcb) * 8];
    }
#pragma unroll
    for (int i = 0; i < 4; i++)
#pragma unroll
      for (int j = 0; j < 4; j++)
        acc[i][j] = __builtin_amdgcn_mfma_f32_16x16x32_bf16(ah[i], bh[j], acc[i][j], 0, 0, 0);
  }

  int lq = lane >> 4;
#pragma unroll
  for (int i = 0; i < 4; i++) {
    int r0 = bm * 128 + wm + i * 16 + lq * 4;
#pragma unroll
    for (int j = 0; j < 4; j++) {
      int cc = bn * 128 + wn + j * 16 + lr;
#pragma unroll
      for (int q = 0; q < 4; q++) {
        int r = r0 + q;
        if (r < Nn) Cb[(size_t)r * C1 + cc] = bf16_rne(acc[i][j][q]);
      }
    }
  }
}

// ------------- per-(node,head) attention logits from bf16 h1 ----------------
__global__ __launch_bounds__(256) void logits1_kernel(
    const unsigned short* __restrict__ h1b, const float* __restrict__ att_s,
    const float* __restrict__ att_d, float* __restrict__ as1, float* __restrict__ ad1)
{
  int wave = threadIdx.x >> 6, lane = threadIdx.x & 63;
  int p = blockIdx.x * 4 + wave;            // pair index n*8+h
  if (p >= Nn * H1n) return;
  int n = p >> 3, h = p & 7;
  float v = bf16_f(h1b[(size_t)n * C1 + h * HIDn + lane]);
  float s = v * att_s[h * HIDn + lane];
  float d = v * att_d[h * HIDn + lane];
#pragma unroll
  for (int off = 32; off; off >>= 1) {
    s += __shfl_xor(s, off);
    d += __shfl_xor(d, off);
  }
  if (lane == 0) { as1[p] = s; ad1[p] = d; }
}

// --------------------------- CSR build by dst -------------------------------
__global__ void hist_kernel(const int* __restrict__ ei, int* __restrict__ cnt)
{
  int e = blockIdx.x * 256 + threadIdx.x;
  if (e >= EPn) return;
  int d = (e < En) ? ei[En + e] : (e - En);
  atomicAdd(&cnt[d], 1);
}

__global__ __launch_bounds__(1024) void scan_kernel(
    const int* __restrict__ cnt, int* __restrict__ row)
{
  __shared__ int wsum[16];
  int t = threadIdx.x;
  int base = t * 20;
  int v[20];
  int s = 0;
#pragma unroll
  for (int j = 0; j < 20; j++) {
    int i = base + j;
    int c = (i < Nn) ? cnt[i] : 0;
    v[j] = s;
    s += c;
  }
  int lane = t & 63, w = t >> 6;
  int incl = s;
#pragma unroll
  for (int off = 1; off < 64; off <<= 1) {
    int o = __shfl_up(incl, off);
    if (lane >= off) incl += o;
  }
  if (lane == 63) wsum[w] = incl;
  __syncthreads();
  if (w == 0) {
    int ws = (lane < 16) ? wsum[lane] : 0;
#pragma unroll
    for (int off = 1; off < 16; off <<= 1) {
      int o = __shfl_up(ws, off);
      if (lane >= off) ws += o;
    }
    if (lane < 16) wsum[lane] = ws;
  }
  __syncthreads();
  int excl = ((w > 0) ? wsum[w - 1] : 0) + incl - s;
#pragma unroll
  for (int j = 0; j < 20; j++) {
    int i = base + j;
    if (i < Nn) row[i] = excl + v[j];
  }
  if (t == 0) row[Nn] = EPn;
}

__global__ void scatter_kernel(const int* __restrict__ ei, const int* __restrict__ row,
                               int* __restrict__ cur, int* __restrict__ csr)
{
  int e = blockIdx.x * 256 + threadIdx.x;
  if (e >= EPn) return;
  int s, d;
  if (e < En) { s = ei[e]; d = ei[En + e]; }
  else        { s = e - En; d = e - En; }
  int pos = row[d] + atomicAdd(&cur[d], 1);
  csr[pos] = s;
}

// ----- layer-1 fused softmax-gather, SINGLE PASS, one wave per dst ----------
// softmax(x) = exp(x)/sum(exp(x)) -- no max-shift needed (logits bounded |v|<~10,
// identical function, reference's max-subtract cancels), and the division can
// happen AFTER aggregation: out = (sum_e p_e * h[src_e]) / z.  Every lane
// iterates ALL edges, so z needs no reduction.  Lane owns 8 channels
// (head = lane>>3).  No LDS, no barriers, no shuffles.
__global__ __launch_bounds__(256) void agg1_kernel(
    const int* __restrict__ row, const int* __restrict__ csr,
    const unsigned short* __restrict__ h1b, const float* __restrict__ as1,
    const float* __restrict__ adv, const float* __restrict__ b1,
    unsigned short* __restrict__ outb)
{
  int wv = threadIdx.x >> 6, lane = threadIdx.x & 63;
  int d = blockIdx.x * 4 + wv;        // grid = N/4 exactly
  int beg = row[d], end = row[d + 1];
  int hq = lane >> 3;                 // this lane's head (8 ch/lane)
  size_t chb = (size_t)8 * lane;
  float adH = adv[d * 8 + hq];

  float a0 = 0.f, a1 = 0.f, a2 = 0.f, a3 = 0.f;
  float a4 = 0.f, a5 = 0.f, a6 = 0.f, a7 = 0.f;
  float z = 0.f;
#pragma unroll 4
  for (int e = beg; e < end; e++) {
    int s = csr[e];                   // wave-uniform broadcast load
    float v = as1[s * 8 + hq] + adH;  // 8 distinct addrs per wave
    v = (v >= 0.f) ? v : NEG * v;
    float p = __expf(v);              // unnormalized; z divides at the end
    z += p;
    uint4 u = *(const uint4*)&h1b[(size_t)s * C1 + chb];
    a0 = fmaf(p, __uint_as_float(u.x << 16), a0);
    a1 = fmaf(p, __uint_as_float(u.x & 0xffff0000u), a1);
    a2 = fmaf(p, __uint_as_float(u.y << 16), a2);
    a3 = fmaf(p, __uint_as_float(u.y & 0xffff0000u), a3);
    a4 = fmaf(p, __uint_as_float(u.z << 16), a4);
    a5 = fmaf(p, __uint_as_float(u.z & 0xffff0000u), a5);
    a6 = fmaf(p, __uint_as_float(u.w << 16), a6);
    a7 = fmaf(p, __uint_as_float(u.w & 0xffff0000u), a7);
  }

  float rz = 1.f / z;                 // deg >= 1 (self-loop) => z > 0
  float4 b0 = *(const float4*)&b1[chb];
  float4 b4 = *(const float4*)&b1[chb + 4];
  float o[8] = {fmaf(a0, rz, b0.x), fmaf(a1, rz, b0.y),
                fmaf(a2, rz, b0.z), fmaf(a3, rz, b0.w),
                fmaf(a4, rz, b4.x), fmaf(a5, rz, b4.y),
                fmaf(a6, rz, b4.z), fmaf(a7, rz, b4.w)};
  unsigned short r[8];
#pragma unroll
  for (int i = 0; i < 8; i++) r[i] = bf16_rne(o[i] > 0.f ? o[i] : 0.f);
  ushort4 r0 = {r[0], r[1], r[2], r[3]}, r4 = {r[4], r[5], r[6], r[7]};
  *(ushort4*)&outb[(size_t)d * C1 + chb] = r0;
  *(ushort4*)&outb[(size_t)d * C1 + chb + 4] = r4;
}

// --------- layer-2 transform: h2[N,16] = relu1b @ W2^T; a_s2, a_d2 ----------
__global__ __launch_bounds__(256) void l2_kernel(
    const unsigned short* __restrict__ in, const float* __restrict__ W2,
    const float* __restrict__ att_s, const float* __restrict__ att_d,
    float* __restrict__ h2, float* __restrict__ as2, float* __restrict__ ad2)
{
  __shared__ float W2s[OUT_CH * 512];
  int t = threadIdx.x;
  for (int i = t * 4; i < OUT_CH * 512; i += 1024)
    *(float4*)&W2s[i] = *(const float4*)&W2[i];
  __syncthreads();
  int wave = t >> 6, lane = t & 63;
  int n = blockIdx.x * 4 + wave;   // grid = N/4 exactly
  const unsigned short* xr = in + (size_t)n * 512;
  float acc[16] = {};
  for (int k = lane; k < 512; k += 64) {
    float xv = bf16_f(xr[k]);
#pragma unroll
    for (int j = 0; j < 16; j++) acc[j] = fmaf(xv, W2s[j * 512 + k], acc[j]);
  }
#pragma unroll
  for (int j = 0; j < 16; j++)
#pragma unroll
    for (int off = 32; off; off >>= 1) acc[j] += __shfl_xor(acc[j], off);
  if (lane == 0) {
    float s = 0.f, dd = 0.f;
#pragma unroll
    for (int j = 0; j < 16; j++) {
      h2[(size_t)n * 16 + j] = acc[j];
      s  = fmaf(acc[j], att_s[j], s);
      dd = fmaf(acc[j], att_d[j], dd);
    }
    as2[n] = s; ad2[n] = dd;
  }
}

// ------- layer-2 single-pass softmax-gather (one wave per dst), +b2 ---------
__global__ __launch_bounds__(256) void agg2_kernel(
    const int* __restrict__ row, const int* __restrict__ csr,
    const float* __restrict__ h2, const float* __restrict__ as2,
    const float* __restrict__ ad2, const float* __restrict__ b2,
    float* __restrict__ out)
{
  int wave = threadIdx.x >> 6, lane = threadIdx.x & 63;
  int d = blockIdx.x * 4 + wave;   // grid = N/4 exactly
  int beg = row[d], end = row[d + 1];
  float add = ad2[d];

  int c = lane & 15;
  float acc = 0.f, z = 0.f;
  for (int e = beg + (lane >> 4); e < end; e += 4) {
    int s = csr[e];
    float v = as2[s] + add;
    v = (v >= 0.f) ? v : NEG * v;
    float p = __expf(v);
    z += p;
    acc = fmaf(p, h2[(size_t)s * 16 + c], acc);
  }
  acc += __shfl_xor(acc, 16);
  acc += __shfl_xor(acc, 32);
  z += __shfl_xor(z, 16);
  z += __shfl_xor(z, 32);
  if (lane < 16) out[(size_t)d * 16 + lane] = acc / z + b2[lane];
}

extern "C" void kernel_launch(void* const* d_in, const int* in_sizes, int n_in,
                              void* d_out, int out_size, void* d_ws, size_t ws_size,
                              hipStream_t stream)
{
  const float* x    = (const float*)d_in[0];
  const int*   ei   = (const int*)d_in[1];
  const float* W1   = (const float*)d_in[2];
  const float* asv1 = (const float*)d_in[3];
  const float* adv1 = (const float*)d_in[4];
  const float* b1   = (const float*)d_in[5];
  const float* W2   = (const float*)d_in[6];
  const float* asv2 = (const float*)d_in[7];
  const float* adv2 = (const float*)d_in[8];
  const float* b2   = (const float*)d_in[9];
  float* out = (float*)d_out;

  // workspace layout (16B-aligned regions), ~46 MB total
  unsigned short* h1b    = (unsigned short*)d_ws;             // N*512 bf16
  unsigned short* relu1b = h1b + (size_t)Nn * C1;             // N*512 bf16 (aliased x_b pre-agg1)
  unsigned short* w_b    = relu1b + (size_t)Nn * C1;          // 512*512 bf16
  float* as1   = (float*)(w_b + (size_t)C1 * IN_CH);          // N*8
  float* ad1   = as1 + (size_t)Nn * H1n;                      // N*8
  float* h2    = ad1 + (size_t)Nn * H1n;                      // N*16
  float* as2   = h2 + (size_t)Nn * OUT_CH;                    // N
  float* ad2   = as2 + Nn;                                    // N
  int* csr  = (int*)(ad2 + Nn);                               // E+N
  int* cnt  = csr + EPn;                                      // N
  int* rowp = cnt + Nn;                                       // N+1
  int* cur  = rowp + Nn + 1;                                  // N

  unsigned short* x_b = (unsigned short*)relu1b;              // N*512 bf16

  hipMemsetAsync(cnt, 0, Nn * sizeof(int), stream);
  hipMemsetAsync(cur, 0, Nn * sizeof(int), stream);

  cvt2_kernel<<<(NX8 + NW8 + 255) / 256, 256, 0, stream>>>(x, x_b, W1, w_b);

  dim3 g1(157, 4);
  gemm1_mfma<<<g1, 256, 0, stream>>>(x_b, w_b, h1b);

  logits1_kernel<<<(Nn * H1n) / 4, 256, 0, stream>>>(h1b, asv1, adv1, as1, ad1);
  hist_kernel<<<(EPn + 255) / 256, 256, 0, stream>>>(ei, cnt);
  scan_kernel<<<1, 1024, 0, stream>>>(cnt, rowp);
  scatter_kernel<<<(EPn + 255) / 256, 256, 0, stream>>>(ei, rowp, cur, csr);
  agg1_kernel<<<Nn / 4, 256, 0, stream>>>(rowp, csr, h1b, as1, ad1, b1, relu1b);  // overwrites x_b (gemm done)
  l2_kernel<<<Nn / 4, 256, 0, stream>>>(relu1b, W2, asv2, adv2, h2, as2, ad2);
  agg2_kernel<<<Nn / 4, 256, 0, stream>>>(rowp, csr, h2, as2, ad2, b2, out);
}

// Round 10
// 171.310 us; speedup vs baseline: 1.6319x; 1.2704x over previous
//
#include <hip/hip_runtime.h>

#define Nn     20000
#define IN_CH  512
#define C1     512      // H1*HID
#define H1n    8
#define HIDn   64
#define OUT_CH 16
#define En     320000
#define EPn    340000   // E + N self-loops
#define NEG    0.2f

typedef __attribute__((ext_vector_type(8))) short bf16x8;
typedef __attribute__((ext_vector_type(4))) float f32x4;

// ---------------- fp32 -> bf16 helpers (RNE) --------------------------------
__device__ inline unsigned short bf16_rne(float f) {
  unsigned int u = __float_as_uint(f);
  return (unsigned short)((u + 0x7fffu + ((u >> 16) & 1u)) >> 16);
}
__device__ inline float bf16_f(unsigned short u) {
  return __uint_as_float(((unsigned int)u) << 16);
}

// x, W1, W2 -> bf16 in one launch
#define NX8  (Nn * IN_CH / 8)
#define NW8  (C1 * IN_CH / 8)
#define NW28 (OUT_CH * C1 / 8)
__global__ __launch_bounds__(256) void cvt3_kernel(
    const float* __restrict__ x,  unsigned short* __restrict__ xb,
    const float* __restrict__ W1, unsigned short* __restrict__ w1b,
    const float* __restrict__ W2, unsigned short* __restrict__ w2b)
{
  int i = blockIdx.x * 256 + threadIdx.x;
  const float* in; unsigned short* ob; int idx;
  if (i < NX8) { in = x; ob = xb; idx = i; }
  else if (i < NX8 + NW8) { in = W1; ob = w1b; idx = i - NX8; }
  else if (i < NX8 + NW8 + NW28) { in = W2; ob = w2b; idx = i - NX8 - NW8; }
  else return;
  float4 f0 = ((const float4*)in)[idx * 2];
  float4 f1 = ((const float4*)in)[idx * 2 + 1];
  float f[8] = {f0.x, f0.y, f0.z, f0.w, f1.x, f1.y, f1.z, f1.w};
  unsigned short h[8];
#pragma unroll
  for (int j = 0; j < 8; j++) h[j] = bf16_rne(f[j]);
  ushort4 hv0 = {h[0], h[1], h[2], h[3]}, hv1 = {h[4], h[5], h[6], h[7]};
  ((ushort4*)ob)[idx * 2] = hv0; ((ushort4*)ob)[idx * 2 + 1] = hv1;
}

// ------ GEMM1 (bf16 MFMA) + fused attention logits --------------------------
// h1b[N,512](bf16) = x @ W1^T; as1/ad1[N,8] = (h1 . att_src/dst) per head.
// Each wave owns a 64x64 subtile whose 64 cols == ONE head => logits are
// wave-local: 4 fma + 4-step shfl per row, direct stores, no atomics.
#define GLL(gp, lp) __builtin_amdgcn_global_load_lds( \
    (const __attribute__((address_space(1))) void*)(gp), \
    (__attribute__((address_space(3))) void*)(lp), 16, 0, 0)

// involutive chunk swizzle: spreads 64B-stride rows across all 8 bank groups
#define SWZ(c) ((c) ^ (((c) >> 3) & 3))

__global__ __launch_bounds__(256, 2) void gemm1_mfma(
    const unsigned short* __restrict__ Ab, const unsigned short* __restrict__ Bb,
    const float* __restrict__ attS, const float* __restrict__ attD,
    unsigned short* __restrict__ Cb, float* __restrict__ as1, float* __restrict__ ad1)
{
  __shared__ unsigned short sA[128 * 32], sB[128 * 32];
  int t = threadIdx.x;
  int bm = blockIdx.x, bn = blockIdx.y;
  int lane = t & 63, w = t >> 6;

  // staging: 512 16B-chunks per tile; LDS slot q holds tile-chunk SWZ(q)
  int slot0 = w * 128 + lane;
  int slot1 = slot0 + 64;
  int cb0 = w * 128, cb1 = w * 128 + 64;     // wave-uniform LDS base chunks
  int cs0 = SWZ(slot0), cs1 = SWZ(slot1);    // tile-chunk fetched by this lane
  int ar0 = bm * 128 + (cs0 >> 2); if (ar0 > Nn - 1) ar0 = Nn - 1;
  int ar1 = bm * 128 + (cs1 >> 2); if (ar1 > Nn - 1) ar1 = Nn - 1;
  int br0 = bn * 128 + (cs0 >> 2);
  int br1 = bn * 128 + (cs1 >> 2);
  size_t offA0 = (size_t)ar0 * IN_CH + (cs0 & 3) * 8;
  size_t offA1 = (size_t)ar1 * IN_CH + (cs1 & 3) * 8;
  size_t offB0 = (size_t)br0 * IN_CH + (cs0 & 3) * 8;
  size_t offB1 = (size_t)br1 * IN_CH + (cs1 & 3) * 8;

  int wm = (w >> 1) * 64, wn = (w & 1) * 64;
  int lr = lane & 15, kb = lane >> 4;

  f32x4 acc[4][4] = {};

  for (int k0 = 0; k0 < IN_CH; k0 += 32) {
    __syncthreads();                      // prev iter's LDS reads done
    GLL(Ab + offA0 + k0, sA + cb0 * 8);
    GLL(Ab + offA1 + k0, sA + cb1 * 8);
    GLL(Bb + offB0 + k0, sB + cb0 * 8);
    GLL(Bb + offB1 + k0, sB + cb1 * 8);
    __syncthreads();                      // loads landed

    bf16x8 ah[4], bh[4];
#pragma unroll
    for (int i = 0; i < 4; i++) {
      int rca = (wm + i * 16 + lr) * 4 + kb;
      ah[i] = *(const bf16x8*)&sA[SWZ(rca) * 8];
      int rcb = (wn + i * 16 + lr) * 4 + kb;
      bh[i] = *(const bf16x8*)&sB[SWZ(rcb) * 8];
    }
#pragma unroll
    for (int i = 0; i < 4; i++)
#pragma unroll
      for (int j = 0; j < 4; j++)
        acc[i][j] = __builtin_amdgcn_mfma_f32_16x16x32_bf16(ah[i], bh[j], acc[i][j], 0, 0, 0);
  }

  int lq = lane >> 4;
  // C store
#pragma unroll
  for (int i = 0; i < 4; i++) {
    int r0 = bm * 128 + wm + i * 16 + lq * 4;
#pragma unroll
    for (int j = 0; j < 4; j++) {
      int cc = bn * 128 + wn + j * 16 + lr;
#pragma unroll
      for (int q = 0; q < 4; q++) {
        int r = r0 + q;
        if (r < Nn) Cb[(size_t)r * C1 + cc] = bf16_rne(acc[i][j][q]);
      }
    }
  }
  // fused logits: this wave's cols are head hh, channels (j*16+lr) within it
  int hh = bn * 2 + (wn >> 6);
  float aSj[4], aDj[4];
#pragma unroll
  for (int j = 0; j < 4; j++) {
    int cc = bn * 128 + wn + j * 16 + lr;
    aSj[j] = attS[cc]; aDj[j] = attD[cc];
  }
#pragma unroll
  for (int i = 0; i < 4; i++)
#pragma unroll
    for (int q = 0; q < 4; q++) {
      float s = acc[i][0][q] * aSj[0] + acc[i][1][q] * aSj[1]
              + acc[i][2][q] * aSj[2] + acc[i][3][q] * aSj[3];
      float dd = acc[i][0][q] * aDj[0] + acc[i][1][q] * aDj[1]
               + acc[i][2][q] * aDj[2] + acc[i][3][q] * aDj[3];
#pragma unroll
      for (int off = 1; off < 16; off <<= 1) {
        s += __shfl_xor(s, off);
        dd += __shfl_xor(dd, off);
      }
      int r = bm * 128 + wm + i * 16 + lq * 4 + q;
      if (lr == 0 && r < Nn) { as1[r * 8 + hh] = s; ad1[r * 8 + hh] = dd; }
    }
}

// --------------------------- CSR build by dst -------------------------------
__global__ void hist_kernel(const int* __restrict__ ei, int* __restrict__ cnt)
{
  int e = blockIdx.x * 256 + threadIdx.x;
  if (e >= EPn) return;
  int d = (e < En) ? ei[En + e] : (e - En);
  atomicAdd(&cnt[d], 1);
}

__global__ __launch_bounds__(1024) void scan_kernel(
    const int* __restrict__ cnt, int* __restrict__ row)
{
  __shared__ int wsum[16];
  int t = threadIdx.x;
  int base = t * 20;
  int v[20];
  int s = 0;
#pragma unroll
  for (int j = 0; j < 20; j++) {
    int i = base + j;
    int c = (i < Nn) ? cnt[i] : 0;
    v[j] = s;
    s += c;
  }
  int lane = t & 63, w = t >> 6;
  int incl = s;
#pragma unroll
  for (int off = 1; off < 64; off <<= 1) {
    int o = __shfl_up(incl, off);
    if (lane >= off) incl += o;
  }
  if (lane == 63) wsum[w] = incl;
  __syncthreads();
  if (w == 0) {
    int ws = (lane < 16) ? wsum[lane] : 0;
#pragma unroll
    for (int off = 1; off < 16; off <<= 1) {
      int o = __shfl_up(ws, off);
      if (lane >= off) ws += o;
    }
    if (lane < 16) wsum[lane] = ws;
  }
  __syncthreads();
  int excl = ((w > 0) ? wsum[w - 1] : 0) + incl - s;
#pragma unroll
  for (int j = 0; j < 20; j++) {
    int i = base + j;
    if (i < Nn) row[i] = excl + v[j];
  }
  if (t == 0) row[Nn] = EPn;
}

__global__ void scatter_kernel(const int* __restrict__ ei, const int* __restrict__ row,
                               int* __restrict__ cur, int* __restrict__ csr)
{
  int e = blockIdx.x * 256 + threadIdx.x;
  if (e >= EPn) return;
  int s, d;
  if (e < En) { s = ei[e]; d = ei[En + e]; }
  else        { s = e - En; d = e - En; }
  int pos = row[d] + atomicAdd(&cur[d], 1);
  csr[pos] = s;
}

// ----- layer-1 fused softmax-gather, SINGLE PASS, one wave per dst ----------
// softmax(x) = exp(x)/sum(exp(x)) -- no max-shift needed (logits bounded),
// and the z-division happens AFTER aggregation.  Every lane iterates ALL
// edges, so z needs no reduction.  Lane owns 8 channels (head = lane>>3).
// No LDS, no barriers, no shuffles.
__global__ __launch_bounds__(256) void agg1_kernel(
    const int* __restrict__ row, const int* __restrict__ csr,
    const unsigned short* __restrict__ h1b, const float* __restrict__ as1,
    const float* __restrict__ adv, const float* __restrict__ b1,
    unsigned short* __restrict__ outb)
{
  int wv = threadIdx.x >> 6, lane = threadIdx.x & 63;
  int d = blockIdx.x * 4 + wv;        // grid = N/4 exactly
  int beg = row[d], end = row[d + 1];
  int hq = lane >> 3;                 // this lane's head (8 ch/lane)
  size_t chb = (size_t)8 * lane;
  float adH = adv[d * 8 + hq];

  float a0 = 0.f, a1 = 0.f, a2 = 0.f, a3 = 0.f;
  float a4 = 0.f, a5 = 0.f, a6 = 0.f, a7 = 0.f;
  float z = 0.f;
#pragma unroll 4
  for (int e = beg; e < end; e++) {
    int s = csr[e];                   // wave-uniform broadcast load
    float v = as1[s * 8 + hq] + adH;  // 8 distinct addrs per wave
    v = (v >= 0.f) ? v : NEG * v;
    float p = __expf(v);              // unnormalized; z divides at the end
    z += p;
    uint4 u = *(const uint4*)&h1b[(size_t)s * C1 + chb];
    a0 = fmaf(p, __uint_as_float(u.x << 16), a0);
    a1 = fmaf(p, __uint_as_float(u.x & 0xffff0000u), a1);
    a2 = fmaf(p, __uint_as_float(u.y << 16), a2);
    a3 = fmaf(p, __uint_as_float(u.y & 0xffff0000u), a3);
    a4 = fmaf(p, __uint_as_float(u.z << 16), a4);
    a5 = fmaf(p, __uint_as_float(u.z & 0xffff0000u), a5);
    a6 = fmaf(p, __uint_as_float(u.w << 16), a6);
    a7 = fmaf(p, __uint_as_float(u.w & 0xffff0000u), a7);
  }

  float rz = 1.f / z;                 // deg >= 1 (self-loop) => z > 0
  float4 b0 = *(const float4*)&b1[chb];
  float4 b4 = *(const float4*)&b1[chb + 4];
  float o[8] = {fmaf(a0, rz, b0.x), fmaf(a1, rz, b0.y),
                fmaf(a2, rz, b0.z), fmaf(a3, rz, b0.w),
                fmaf(a4, rz, b4.x), fmaf(a5, rz, b4.y),
                fmaf(a6, rz, b4.z), fmaf(a7, rz, b4.w)};
  unsigned short r[8];
#pragma unroll
  for (int i = 0; i < 8; i++) r[i] = bf16_rne(o[i] > 0.f ? o[i] : 0.f);
  ushort4 r0 = {r[0], r[1], r[2], r[3]}, r4 = {r[4], r[5], r[6], r[7]};
  *(ushort4*)&outb[(size_t)d * C1 + chb] = r0;
  *(ushort4*)&outb[(size_t)d * C1 + chb + 4] = r4;
}

// --------- layer-2 transform (MFMA): h2[N,16] = relu1b @ W2^T ---------------
// One 16-row tile per wave; B-frags (W2b, [n][k] layout like gemm1's B)
// preloaded; 16 MFMA over K=512.  Epilogue: h2 + as2/ad2 via 16-lane reduce.
__global__ __launch_bounds__(256) void l2_mfma(
    const unsigned short* __restrict__ Xb, const unsigned short* __restrict__ W2b,
    const float* __restrict__ att_s, const float* __restrict__ att_d,
    float* __restrict__ h2, float* __restrict__ as2, float* __restrict__ ad2)
{
  int w = threadIdx.x >> 6, lane = threadIdx.x & 63;
  int tile = blockIdx.x * 4 + w;
  if (tile >= Nn / 16) return;          // 1250 tiles
  int n0 = tile * 16;
  int lr = lane & 15, kb = lane >> 4;

  bf16x8 bf[16];
#pragma unroll
  for (int k0 = 0; k0 < 16; k0++)
    bf[k0] = *(const bf16x8*)&W2b[lr * 512 + kb * 8 + k0 * 32];

  f32x4 acc = {0.f, 0.f, 0.f, 0.f};
#pragma unroll
  for (int k0 = 0; k0 < 16; k0++) {
    bf16x8 af = *(const bf16x8*)&Xb[(size_t)(n0 + lr) * 512 + kb * 8 + k0 * 32];
    acc = __builtin_amdgcn_mfma_f32_16x16x32_bf16(af, bf[k0], acc, 0, 0, 0);
  }

  float aS = att_s[lr], aD = att_d[lr];   // col = lr
#pragma unroll
  for (int r = 0; r < 4; r++) {
    int n = n0 + kb * 4 + r;
    h2[(size_t)n * 16 + lr] = acc[r];
    float sv = acc[r] * aS, dv = acc[r] * aD;
#pragma unroll
    for (int off = 1; off < 16; off <<= 1) {
      sv += __shfl_xor(sv, off);
      dv += __shfl_xor(dv, off);
    }
    if (lr == 0) { as2[n] = sv; ad2[n] = dv; }
  }
}

// ------- layer-2 single-pass softmax-gather (one wave per dst), +b2 ---------
__global__ __launch_bounds__(256) void agg2_kernel(
    const int* __restrict__ row, const int* __restrict__ csr,
    const float* __restrict__ h2, const float* __restrict__ as2,
    const float* __restrict__ ad2, const float* __restrict__ b2,
    float* __restrict__ out)
{
  int wave = threadIdx.x >> 6, lane = threadIdx.x & 63;
  int d = blockIdx.x * 4 + wave;   // grid = N/4 exactly
  int beg = row[d], end = row[d + 1];
  float add = ad2[d];

  int c = lane & 15;
  float acc = 0.f, z = 0.f;
  for (int e = beg + (lane >> 4); e < end; e += 4) {
    int s = csr[e];
    float v = as2[s] + add;
    v = (v >= 0.f) ? v : NEG * v;
    float p = __expf(v);
    z += p;
    acc = fmaf(p, h2[(size_t)s * 16 + c], acc);
  }
  acc += __shfl_xor(acc, 16);
  acc += __shfl_xor(acc, 32);
  z += __shfl_xor(z, 16);
  z += __shfl_xor(z, 32);
  if (lane < 16) out[(size_t)d * 16 + lane] = acc / z + b2[lane];
}

extern "C" void kernel_launch(void* const* d_in, const int* in_sizes, int n_in,
                              void* d_out, int out_size, void* d_ws, size_t ws_size,
                              hipStream_t stream)
{
  const float* x    = (const float*)d_in[0];
  const int*   ei   = (const int*)d_in[1];
  const float* W1   = (const float*)d_in[2];
  const float* asv1 = (const float*)d_in[3];
  const float* adv1 = (const float*)d_in[4];
  const float* b1   = (const float*)d_in[5];
  const float* W2   = (const float*)d_in[6];
  const float* asv2 = (const float*)d_in[7];
  const float* adv2 = (const float*)d_in[8];
  const float* b2   = (const float*)d_in[9];
  float* out = (float*)d_out;

  // workspace layout (16B-aligned regions)
  unsigned short* h1b    = (unsigned short*)d_ws;             // N*512 bf16
  unsigned short* relu1b = h1b + (size_t)Nn * C1;             // N*512 bf16 (aliased x_b pre-agg1)
  unsigned short* w_b    = relu1b + (size_t)Nn * C1;          // 512*512 bf16
  unsigned short* w2b    = w_b + (size_t)C1 * IN_CH;          // 16*512 bf16
  float* as1   = (float*)(w2b + (size_t)OUT_CH * C1);         // N*8
  float* ad1   = as1 + (size_t)Nn * H1n;                      // N*8
  float* h2    = ad1 + (size_t)Nn * H1n;                      // N*16
  float* as2   = h2 + (size_t)Nn * OUT_CH;                    // N
  float* ad2   = as2 + Nn;                                    // N
  int* csr  = (int*)(ad2 + Nn);                               // E+N
  int* cnt  = csr + EPn;                                      // N
  int* rowp = cnt + Nn;                                       // N+1
  int* cur  = rowp + Nn + 1;                                  // N

  unsigned short* x_b = (unsigned short*)relu1b;              // N*512 bf16

  hipMemsetAsync(cnt, 0, Nn * sizeof(int), stream);
  hipMemsetAsync(cur, 0, Nn * sizeof(int), stream);

  cvt3_kernel<<<(NX8 + NW8 + NW28 + 255) / 256, 256, 0, stream>>>(
      x, x_b, W1, w_b, W2, w2b);

  dim3 g1(157, 4);
  gemm1_mfma<<<g1, 256, 0, stream>>>(x_b, w_b, asv1, adv1, h1b, as1, ad1);

  hist_kernel<<<(EPn + 255) / 256, 256, 0, stream>>>(ei, cnt);
  scan_kernel<<<1, 1024, 0, stream>>>(cnt, rowp);
  scatter_kernel<<<(EPn + 255) / 256, 256, 0, stream>>>(ei, rowp, cur, csr);
  agg1_kernel<<<Nn / 4, 256, 0, stream>>>(rowp, csr, h1b, as1, ad1, b1, relu1b);  // overwrites x_b (gemm done)
  l2_mfma<<<(Nn / 16 + 3) / 4, 256, 0, stream>>>(relu1b, w2b, asv2, adv2, h2, as2, ad2);
  agg2_kernel<<<Nn / 4, 256, 0, stream>>>(rowp, csr, h2, as2, ad2, b2, out);
}

// Round 11
// 164.525 us; speedup vs baseline: 1.6992x; 1.0412x over previous
//
#include <hip/hip_runtime.h>

#define Nn     20000
#define IN_CH  512
#define C1     512      // H1*HID
#define H1n    8
#define HIDn   64
#define OUT_CH 16
#define En     320000
#define EPn    340000   // E + N self-loops
#define NEG    0.2f

typedef __attribute__((ext_vector_type(8))) short bf16x8;
typedef __attribute__((ext_vector_type(4))) float f32x4;

// ---------------- fp32 -> bf16 helpers (RNE) --------------------------------
__device__ inline unsigned short bf16_rne(float f) {
  unsigned int u = __float_as_uint(f);
  return (unsigned short)((u + 0x7fffu + ((u >> 16) & 1u)) >> 16);
}
__device__ inline float bf16_f(unsigned short u) {
  return __uint_as_float(((unsigned int)u) << 16);
}

// x, W1, W2 -> bf16 in one launch
#define NX8  (Nn * IN_CH / 8)
#define NW8  (C1 * IN_CH / 8)
#define NW28 (OUT_CH * C1 / 8)
__global__ __launch_bounds__(256) void cvt3_kernel(
    const float* __restrict__ x,  unsigned short* __restrict__ xb,
    const float* __restrict__ W1, unsigned short* __restrict__ w1b,
    const float* __restrict__ W2, unsigned short* __restrict__ w2b)
{
  int i = blockIdx.x * 256 + threadIdx.x;
  const float* in; unsigned short* ob; int idx;
  if (i < NX8) { in = x; ob = xb; idx = i; }
  else if (i < NX8 + NW8) { in = W1; ob = w1b; idx = i - NX8; }
  else if (i < NX8 + NW8 + NW28) { in = W2; ob = w2b; idx = i - NX8 - NW8; }
  else return;
  float4 f0 = ((const float4*)in)[idx * 2];
  float4 f1 = ((const float4*)in)[idx * 2 + 1];
  float f[8] = {f0.x, f0.y, f0.z, f0.w, f1.x, f1.y, f1.z, f1.w};
  unsigned short h[8];
#pragma unroll
  for (int j = 0; j < 8; j++) h[j] = bf16_rne(f[j]);
  ushort4 hv0 = {h[0], h[1], h[2], h[3]}, hv1 = {h[4], h[5], h[6], h[7]};
  ((ushort4*)ob)[idx * 2] = hv0; ((ushort4*)ob)[idx * 2 + 1] = hv1;
}

// ------ GEMM1 (bf16 MFMA) + fused attention logits --------------------------
// h1b[N,512](bf16) = x @ W1^T; as1/ad1[N,8] = (h1 . att_src/dst) per head.
// Each wave owns a 64x64 subtile whose 64 cols == ONE head => logits are
// wave-local.  628 blocks at 3 blocks/CU => all co-resident, no tail.
#define GLL(gp, lp) __builtin_amdgcn_global_load_lds( \
    (const __attribute__((address_space(1))) void*)(gp), \
    (__attribute__((address_space(3))) void*)(lp), 16, 0, 0)

// involutive chunk swizzle: spreads 64B-stride rows across all 8 bank groups
#define SWZ(c) ((c) ^ (((c) >> 3) & 3))

__global__ __launch_bounds__(256, 3) void gemm1_mfma(
    const unsigned short* __restrict__ Ab, const unsigned short* __restrict__ Bb,
    const float* __restrict__ attS, const float* __restrict__ attD,
    unsigned short* __restrict__ Cb, float* __restrict__ as1, float* __restrict__ ad1)
{
  __shared__ unsigned short sA[128 * 32], sB[128 * 32];
  int t = threadIdx.x;
  int bm = blockIdx.x, bn = blockIdx.y;
  int lane = t & 63, w = t >> 6;

  // staging: 512 16B-chunks per tile; LDS slot q holds tile-chunk SWZ(q)
  int slot0 = w * 128 + lane;
  int slot1 = slot0 + 64;
  int cb0 = w * 128, cb1 = w * 128 + 64;     // wave-uniform LDS base chunks
  int cs0 = SWZ(slot0), cs1 = SWZ(slot1);    // tile-chunk fetched by this lane
  int ar0 = bm * 128 + (cs0 >> 2); if (ar0 > Nn - 1) ar0 = Nn - 1;
  int ar1 = bm * 128 + (cs1 >> 2); if (ar1 > Nn - 1) ar1 = Nn - 1;
  int br0 = bn * 128 + (cs0 >> 2);
  int br1 = bn * 128 + (cs1 >> 2);
  size_t offA0 = (size_t)ar0 * IN_CH + (cs0 & 3) * 8;
  size_t offA1 = (size_t)ar1 * IN_CH + (cs1 & 3) * 8;
  size_t offB0 = (size_t)br0 * IN_CH + (cs0 & 3) * 8;
  size_t offB1 = (size_t)br1 * IN_CH + (cs1 & 3) * 8;

  int wm = (w >> 1) * 64, wn = (w & 1) * 64;
  int lr = lane & 15, kb = lane >> 4;

  f32x4 acc[4][4] = {};

  for (int k0 = 0; k0 < IN_CH; k0 += 32) {
    __syncthreads();                      // prev iter's LDS reads done
    GLL(Ab + offA0 + k0, sA + cb0 * 8);
    GLL(Ab + offA1 + k0, sA + cb1 * 8);
    GLL(Bb + offB0 + k0, sB + cb0 * 8);
    GLL(Bb + offB1 + k0, sB + cb1 * 8);
    __syncthreads();                      // loads landed

    bf16x8 ah[4], bh[4];
#pragma unroll
    for (int i = 0; i < 4; i++) {
      int rca = (wm + i * 16 + lr) * 4 + kb;
      ah[i] = *(const bf16x8*)&sA[SWZ(rca) * 8];
      int rcb = (wn + i * 16 + lr) * 4 + kb;
      bh[i] = *(const bf16x8*)&sB[SWZ(rcb) * 8];
    }
#pragma unroll
    for (int i = 0; i < 4; i++)
#pragma unroll
      for (int j = 0; j < 4; j++)
        acc[i][j] = __builtin_amdgcn_mfma_f32_16x16x32_bf16(ah[i], bh[j], acc[i][j], 0, 0, 0);
  }

  int lq = lane >> 4;
  // C store
#pragma unroll
  for (int i = 0; i < 4; i++) {
    int r0 = bm * 128 + wm + i * 16 + lq * 4;
#pragma unroll
    for (int j = 0; j < 4; j++) {
      int cc = bn * 128 + wn + j * 16 + lr;
#pragma unroll
      for (int q = 0; q < 4; q++) {
        int r = r0 + q;
        if (r < Nn) Cb[(size_t)r * C1 + cc] = bf16_rne(acc[i][j][q]);
      }
    }
  }
  // fused logits: this wave's cols are head hh, channels (j*16+lr) within it
  int hh = bn * 2 + (wn >> 6);
  float aSj[4], aDj[4];
#pragma unroll
  for (int j = 0; j < 4; j++) {
    int cc = bn * 128 + wn + j * 16 + lr;
    aSj[j] = attS[cc]; aDj[j] = attD[cc];
  }
#pragma unroll
  for (int i = 0; i < 4; i++)
#pragma unroll
    for (int q = 0; q < 4; q++) {
      float s = acc[i][0][q] * aSj[0] + acc[i][1][q] * aSj[1]
              + acc[i][2][q] * aSj[2] + acc[i][3][q] * aSj[3];
      float dd = acc[i][0][q] * aDj[0] + acc[i][1][q] * aDj[1]
               + acc[i][2][q] * aDj[2] + acc[i][3][q] * aDj[3];
#pragma unroll
      for (int off = 1; off < 16; off <<= 1) {
        s += __shfl_xor(s, off);
        dd += __shfl_xor(dd, off);
      }
      int r = bm * 128 + wm + i * 16 + lq * 4 + q;
      if (lr == 0 && r < Nn) { as1[r * 8 + hh] = s; ad1[r * 8 + hh] = dd; }
    }
}

// --------------------------- CSR build by dst -------------------------------
__global__ void hist_kernel(const int* __restrict__ ei, int* __restrict__ cnt)
{
  int e = blockIdx.x * 256 + threadIdx.x;
  if (e >= EPn) return;
  int d = (e < En) ? ei[En + e] : (e - En);
  atomicAdd(&cnt[d], 1);
}

__global__ __launch_bounds__(1024) void scan_kernel(
    const int* __restrict__ cnt, int* __restrict__ row)
{
  __shared__ int wsum[16];
  int t = threadIdx.x;
  int base = t * 20;
  int v[20];
  int s = 0;
#pragma unroll
  for (int j = 0; j < 20; j++) {
    int i = base + j;
    int c = (i < Nn) ? cnt[i] : 0;
    v[j] = s;
    s += c;
  }
  int lane = t & 63, w = t >> 6;
  int incl = s;
#pragma unroll
  for (int off = 1; off < 64; off <<= 1) {
    int o = __shfl_up(incl, off);
    if (lane >= off) incl += o;
  }
  if (lane == 63) wsum[w] = incl;
  __syncthreads();
  if (w == 0) {
    int ws = (lane < 16) ? wsum[lane] : 0;
#pragma unroll
    for (int off = 1; off < 16; off <<= 1) {
      int o = __shfl_up(ws, off);
      if (lane >= off) ws += o;
    }
    if (lane < 16) wsum[lane] = ws;
  }
  __syncthreads();
  int excl = ((w > 0) ? wsum[w - 1] : 0) + incl - s;
#pragma unroll
  for (int j = 0; j < 20; j++) {
    int i = base + j;
    if (i < Nn) row[i] = excl + v[j];
  }
  if (t == 0) row[Nn] = EPn;
}

__global__ void scatter_kernel(const int* __restrict__ ei, const int* __restrict__ row,
                               int* __restrict__ cur, int* __restrict__ csr)
{
  int e = blockIdx.x * 256 + threadIdx.x;
  if (e >= EPn) return;
  int s, d;
  if (e < En) { s = ei[e]; d = ei[En + e]; }
  else        { s = e - En; d = e - En; }
  int pos = row[d] + atomicAdd(&cur[d], 1);
  csr[pos] = s;
}

// ----- layer-1 fused softmax-gather, single pass, TWO waves per dst ---------
// softmax(x) = exp(x)/sum(exp(x)); z-division after aggregation.  The two
// waves of a pair split edges by parity (serial chain halves, 2x gathers in
// flight); parity-1 wave writes its 8 partials + z to a write-once LDS slice
// (stride 9, conflict-free), ONE barrier, parity-0 wave combines + stores.
__global__ __launch_bounds__(256) void agg1_kernel(
    const int* __restrict__ row, const int* __restrict__ csr,
    const unsigned short* __restrict__ h1b, const float* __restrict__ as1,
    const float* __restrict__ adv, const float* __restrict__ b1,
    unsigned short* __restrict__ outb)
{
  __shared__ float part[2][64 * 9];

  int t = threadIdx.x, lane = t & 63, w = t >> 6;
  int pr = w >> 1;                    // dst pair slot within block
  int p  = w & 1;                     // edge parity this wave consumes
  int d = blockIdx.x * 2 + pr;        // grid = N/2 exactly
  int beg = row[d], end = row[d + 1];
  int deg = end - beg;
  int hq = lane >> 3;                 // this lane's head (8 ch/lane)
  size_t chb = (size_t)8 * lane;
  float adH = adv[d * 8 + hq];

  float a0 = 0.f, a1 = 0.f, a2 = 0.f, a3 = 0.f;
  float a4 = 0.f, a5 = 0.f, a6 = 0.f, a7 = 0.f;
  float z = 0.f;
  int nj = (deg - p + 1) >> 1;        // edges with index parity p
#pragma unroll 4
  for (int j = 0; j < nj; j++) {
    int e = beg + p + 2 * j;
    int s = csr[e];                   // wave-uniform broadcast load
    float v = as1[s * 8 + hq] + adH;  // one 32B line per wave
    v = (v >= 0.f) ? v : NEG * v;
    float pp = __expf(v);             // unnormalized; z divides at the end
    z += pp;
    uint4 u = *(const uint4*)&h1b[(size_t)s * C1 + chb];
    a0 = fmaf(pp, __uint_as_float(u.x << 16), a0);
    a1 = fmaf(pp, __uint_as_float(u.x & 0xffff0000u), a1);
    a2 = fmaf(pp, __uint_as_float(u.y << 16), a2);
    a3 = fmaf(pp, __uint_as_float(u.y & 0xffff0000u), a3);
    a4 = fmaf(pp, __uint_as_float(u.z << 16), a4);
    a5 = fmaf(pp, __uint_as_float(u.z & 0xffff0000u), a5);
    a6 = fmaf(pp, __uint_as_float(u.w << 16), a6);
    a7 = fmaf(pp, __uint_as_float(u.w & 0xffff0000u), a7);
  }

  if (p == 1) {                       // write-once partial slice
    float* ps = &part[pr][lane * 9];
    ps[0] = a0; ps[1] = a1; ps[2] = a2; ps[3] = a3;
    ps[4] = a4; ps[5] = a5; ps[6] = a6; ps[7] = a7; ps[8] = z;
  }
  __syncthreads();
  if (p == 0) {
    const float* ps = &part[pr][lane * 9];
    a0 += ps[0]; a1 += ps[1]; a2 += ps[2]; a3 += ps[3];
    a4 += ps[4]; a5 += ps[5]; a6 += ps[6]; a7 += ps[7]; z += ps[8];
    float rz = 1.f / z;               // deg >= 1 (self-loop) => z > 0
    float4 b0 = *(const float4*)&b1[chb];
    float4 b4 = *(const float4*)&b1[chb + 4];
    float o[8] = {fmaf(a0, rz, b0.x), fmaf(a1, rz, b0.y),
                  fmaf(a2, rz, b0.z), fmaf(a3, rz, b0.w),
                  fmaf(a4, rz, b4.x), fmaf(a5, rz, b4.y),
                  fmaf(a6, rz, b4.z), fmaf(a7, rz, b4.w)};
    unsigned short r[8];
#pragma unroll
    for (int i = 0; i < 8; i++) r[i] = bf16_rne(o[i] > 0.f ? o[i] : 0.f);
    ushort4 r0 = {r[0], r[1], r[2], r[3]}, r4 = {r[4], r[5], r[6], r[7]};
    *(ushort4*)&outb[(size_t)d * C1 + chb] = r0;
    *(ushort4*)&outb[(size_t)d * C1 + chb + 4] = r4;
  }
}

// --------- layer-2 transform (MFMA): h2[N,16] = relu1b @ W2^T ---------------
__global__ __launch_bounds__(256) void l2_mfma(
    const unsigned short* __restrict__ Xb, const unsigned short* __restrict__ W2b,
    const float* __restrict__ att_s, const float* __restrict__ att_d,
    float* __restrict__ h2, float* __restrict__ as2, float* __restrict__ ad2)
{
  int w = threadIdx.x >> 6, lane = threadIdx.x & 63;
  int tile = blockIdx.x * 4 + w;
  if (tile >= Nn / 16) return;          // 1250 tiles
  int n0 = tile * 16;
  int lr = lane & 15, kb = lane >> 4;

  bf16x8 bf[16];
#pragma unroll
  for (int k0 = 0; k0 < 16; k0++)
    bf[k0] = *(const bf16x8*)&W2b[lr * 512 + kb * 8 + k0 * 32];

  f32x4 acc = {0.f, 0.f, 0.f, 0.f};
#pragma unroll
  for (int k0 = 0; k0 < 16; k0++) {
    bf16x8 af = *(const bf16x8*)&Xb[(size_t)(n0 + lr) * 512 + kb * 8 + k0 * 32];
    acc = __builtin_amdgcn_mfma_f32_16x16x32_bf16(af, bf[k0], acc, 0, 0, 0);
  }

  float aS = att_s[lr], aD = att_d[lr];   // col = lr
#pragma unroll
  for (int r = 0; r < 4; r++) {
    int n = n0 + kb * 4 + r;
    h2[(size_t)n * 16 + lr] = acc[r];
    float sv = acc[r] * aS, dv = acc[r] * aD;
#pragma unroll
    for (int off = 1; off < 16; off <<= 1) {
      sv += __shfl_xor(sv, off);
      dv += __shfl_xor(dv, off);
    }
    if (lr == 0) { as2[n] = sv; ad2[n] = dv; }
  }
}

// ------- layer-2 single-pass softmax-gather (one wave per dst), +b2 ---------
__global__ __launch_bounds__(256) void agg2_kernel(
    const int* __restrict__ row, const int* __restrict__ csr,
    const float* __restrict__ h2, const float* __restrict__ as2,
    const float* __restrict__ ad2, const float* __restrict__ b2,
    float* __restrict__ out)
{
  int wave = threadIdx.x >> 6, lane = threadIdx.x & 63;
  int d = blockIdx.x * 4 + wave;   // grid = N/4 exactly
  int beg = row[d], end = row[d + 1];
  float add = ad2[d];

  int c = lane & 15;
  float acc = 0.f, z = 0.f;
  for (int e = beg + (lane >> 4); e < end; e += 4) {
    int s = csr[e];
    float v = as2[s] + add;
    v = (v >= 0.f) ? v : NEG * v;
    float p = __expf(v);
    z += p;
    acc = fmaf(p, h2[(size_t)s * 16 + c], acc);
  }
  acc += __shfl_xor(acc, 16);
  acc += __shfl_xor(acc, 32);
  z += __shfl_xor(z, 16);
  z += __shfl_xor(z, 32);
  if (lane < 16) out[(size_t)d * 16 + lane] = acc / z + b2[lane];
}

extern "C" void kernel_launch(void* const* d_in, const int* in_sizes, int n_in,
                              void* d_out, int out_size, void* d_ws, size_t ws_size,
                              hipStream_t stream)
{
  const float* x    = (const float*)d_in[0];
  const int*   ei   = (const int*)d_in[1];
  const float* W1   = (const float*)d_in[2];
  const float* asv1 = (const float*)d_in[3];
  const float* adv1 = (const float*)d_in[4];
  const float* b1   = (const float*)d_in[5];
  const float* W2   = (const float*)d_in[6];
  const float* asv2 = (const float*)d_in[7];
  const float* adv2 = (const float*)d_in[8];
  const float* b2   = (const float*)d_in[9];
  float* out = (float*)d_out;

  // workspace layout (16B-aligned regions)
  unsigned short* h1b    = (unsigned short*)d_ws;             // N*512 bf16
  unsigned short* relu1b = h1b + (size_t)Nn * C1;             // N*512 bf16 (aliased x_b pre-agg1)
  unsigned short* w_b    = relu1b + (size_t)Nn * C1;          // 512*512 bf16
  unsigned short* w2b    = w_b + (size_t)C1 * IN_CH;          // 16*512 bf16
  float* as1   = (float*)(w2b + (size_t)OUT_CH * C1);         // N*8
  float* ad1   = as1 + (size_t)Nn * H1n;                      // N*8
  float* h2    = ad1 + (size_t)Nn * H1n;                      // N*16
  float* as2   = h2 + (size_t)Nn * OUT_CH;                    // N
  float* ad2   = as2 + Nn;                                    // N
  int* csr  = (int*)(ad2 + Nn);                               // E+N
  int* cnt  = csr + EPn;                                      // N   (cnt|cur adjacent:
  int* cur  = cnt + Nn;                                       // N    one memset)
  int* rowp = cur + Nn;                                       // N+1

  unsigned short* x_b = (unsigned short*)relu1b;              // N*512 bf16

  hipMemsetAsync(cnt, 0, 2 * Nn * sizeof(int), stream);

  cvt3_kernel<<<(NX8 + NW8 + NW28 + 255) / 256, 256, 0, stream>>>(
      x, x_b, W1, w_b, W2, w2b);

  dim3 g1(157, 4);
  gemm1_mfma<<<g1, 256, 0, stream>>>(x_b, w_b, asv1, adv1, h1b, as1, ad1);

  hist_kernel<<<(EPn + 255) / 256, 256, 0, stream>>>(ei, cnt);
  scan_kernel<<<1, 1024, 0, stream>>>(cnt, rowp);
  scatter_kernel<<<(EPn + 255) / 256, 256, 0, stream>>>(ei, rowp, cur, csr);
  agg1_kernel<<<Nn / 2, 256, 0, stream>>>(rowp, csr, h1b, as1, ad1, b1, relu1b);  // overwrites x_b (gemm done)
  l2_mfma<<<(Nn / 16 + 3) / 4, 256, 0, stream>>>(relu1b, w2b, asv2, adv2, h2, as2, ad2);
  agg2_kernel<<<Nn / 4, 256, 0, stream>>>(rowp, csr, h2, as2, ad2, b2, out);
}